// Round 4
// baseline (643.067 us; speedup 1.0000x reference)
//
#include <hip/hip_runtime.h>

#define N_NODES 100000
#define N_EDGES 1600000
#define F 128
#define BN_EPS 1e-5f
#define SB 512                                   // deg elements per scan block
#define SCAN_BLOCKS ((N_NODES + SB - 1) / SB)    // 196

// Workspace layout (bytes):
//   [0, 1024)            stats: 256 floats (sum, sumsq)
//   [1024, 401024)       deg:     N_NODES ints
//   [401024, 801040)     offsets: N_NODES+1 ints (padded)
//   [801040, 1201040)    cursor:  N_NODES ints
//   [1201040, 7601040)   csr_src: N_EDGES ints
//   [7601040, 7602064)   bsum:    256 ints
#define O_STATS   0
#define O_DEG     1024
#define O_OFF     401024
#define O_CURSOR  801040
#define O_CSR     1201040
#define O_BSUM    7601040

// ---------------------------------------------------------------------------
// K1: histogram of dst -> deg[]   (4 edges/thread, int4 loads)
// ---------------------------------------------------------------------------
__global__ __launch_bounds__(256) void hist_kernel(
    const int* __restrict__ dst, int* __restrict__ deg)
{
    int e = (blockIdx.x * blockDim.x + threadIdx.x) * 4;
    if (e + 3 < N_EDGES) {
        int4 d4 = *(const int4*)&dst[e];
        atomicAdd(&deg[d4.x], 1);
        atomicAdd(&deg[d4.y], 1);
        atomicAdd(&deg[d4.z], 1);
        atomicAdd(&deg[d4.w], 1);
    } else {
        for (; e < N_EDGES; ++e) atomicAdd(&deg[dst[e]], 1);
    }
}

// ---------------------------------------------------------------------------
// K2a: per-block partial sums of deg (512 elems / block)
// ---------------------------------------------------------------------------
__global__ __launch_bounds__(256) void scan_partial(
    const int* __restrict__ deg, int* __restrict__ bsum)
{
    const int t = threadIdx.x;
    const int i0 = blockIdx.x * SB + t * 2;
    int v0 = (i0 < N_NODES)     ? deg[i0]     : 0;
    int v1 = (i0 + 1 < N_NODES) ? deg[i0 + 1] : 0;
    __shared__ int red[256];
    red[t] = v0 + v1;
    __syncthreads();
    for (int d = 128; d > 0; d >>= 1) {
        if (t < d) red[t] += red[t + d];
        __syncthreads();
    }
    if (t == 0) bsum[blockIdx.x] = red[0];
}

// ---------------------------------------------------------------------------
// K2b: single tiny block: exclusive scan of the block sums (in place)
// ---------------------------------------------------------------------------
__global__ __launch_bounds__(256) void scan_bsum(int* __restrict__ bsum)
{
    const int t = threadIdx.x;
    __shared__ int ls[256];
    int v = (t < SCAN_BLOCKS) ? bsum[t] : 0;
    ls[t] = v;
    __syncthreads();
    for (int d = 1; d < 256; d <<= 1) {
        int u = (t >= d) ? ls[t - d] : 0;
        __syncthreads();
        ls[t] += u;
        __syncthreads();
    }
    if (t < SCAN_BLOCKS) bsum[t] = ls[t] - v;    // exclusive base
}

// ---------------------------------------------------------------------------
// K2c: intra-block exclusive scan + base -> offsets, cursor
// ---------------------------------------------------------------------------
__global__ __launch_bounds__(256) void scan_final(
    const int* __restrict__ deg,
    const int* __restrict__ bsum,
    int* __restrict__ offsets,
    int* __restrict__ cursor)
{
    const int t = threadIdx.x;
    const int i0 = blockIdx.x * SB + t * 2;
    int v0 = (i0 < N_NODES)     ? deg[i0]     : 0;
    int v1 = (i0 + 1 < N_NODES) ? deg[i0 + 1] : 0;
    int s = v0 + v1;
    __shared__ int ls[256];
    ls[t] = s;
    __syncthreads();
    for (int d = 1; d < 256; d <<= 1) {
        int u = (t >= d) ? ls[t - d] : 0;
        __syncthreads();
        ls[t] += u;
        __syncthreads();
    }
    int ex = bsum[blockIdx.x] + ls[t] - s;
    if (i0 < N_NODES)     { offsets[i0]     = ex;      cursor[i0]     = ex; }
    if (i0 + 1 < N_NODES) { offsets[i0 + 1] = ex + v0; cursor[i0 + 1] = ex + v0; }
    if (blockIdx.x == gridDim.x - 1 && t == 255) offsets[N_NODES] = N_EDGES;
}

// ---------------------------------------------------------------------------
// K3: bucket fill: csr_src[cursor[dst]++] = src   (2 edges/thread for ILP)
// ---------------------------------------------------------------------------
__global__ __launch_bounds__(256) void fill_kernel(
    const int* __restrict__ src,
    const int* __restrict__ dst,
    int* __restrict__ cursor,
    int* __restrict__ csr_src)
{
    int e = (blockIdx.x * blockDim.x + threadIdx.x) * 2;
    if (e + 1 < N_EDGES) {
        int2 s2 = *(const int2*)&src[e];
        int2 d2 = *(const int2*)&dst[e];
        int p0 = atomicAdd(&cursor[d2.x], 1);
        int p1 = atomicAdd(&cursor[d2.y], 1);
        csr_src[p0] = s2.x;
        csr_src[p1] = s2.y;
    } else if (e < N_EDGES) {
        int pos = atomicAdd(&cursor[dst[e]], 1);
        csr_src[pos] = src[e];
    }
}

// ---------------------------------------------------------------------------
// K4: FUSED gather + GEMM + BN-stats.
//   Phase 1: gather 64 rows of (A+I)X straight into LDS As.
//   Phase 2: tile GEMM As @ W^T, bias*(deg+1).
//   Epilogue: write out + per-feature sum/sumsq partial -> atomics on stats.
// ---------------------------------------------------------------------------
__global__ __launch_bounds__(256) void fused_agg_gemm(
    const float* __restrict__ X,
    const int* __restrict__ offsets,
    const int* __restrict__ csr_src,
    const float* __restrict__ W,     // [128,128] row-major [out][in]
    const float* __restrict__ bias,  // [128]
    const int* __restrict__ deg,
    float* __restrict__ out,
    float* __restrict__ stats)
{
    __shared__ float As[64 * 132];   // 33.8 KB, full 128-wide A tile
    __shared__ float Ws[32 * 132];   // 16.9 KB, one 32-K chunk of W^T

    const int t    = threadIdx.x;
    const int g    = t >> 5;         // 0..7  (row group / 32-lane group)
    const int lane = t & 31;
    const int c0   = lane * 4;
    const int r0   = g * 8;
    const int row0 = blockIdx.x * 64;

    // ---- Phase 1: gather (A+I)X rows into As -----------------------------
    const float4* X4 = (const float4*)X;
    for (int rr = g; rr < 64; rr += 8) {
        int node = row0 + rr;
        float4 acc = make_float4(0.f, 0.f, 0.f, 0.f);
        if (node < N_NODES) {
            acc = X4[(size_t)node * 32 + lane];          // self loop
            int beg = offsets[node];
            int end = offsets[node + 1];
            int e = beg;
            for (; e + 3 < end; e += 4) {
                int s0 = csr_src[e];
                int s1 = csr_src[e + 1];
                int s2 = csr_src[e + 2];
                int s3 = csr_src[e + 3];
                float4 v0 = X4[(size_t)s0 * 32 + lane];
                float4 v1 = X4[(size_t)s1 * 32 + lane];
                float4 v2 = X4[(size_t)s2 * 32 + lane];
                float4 v3 = X4[(size_t)s3 * 32 + lane];
                acc.x += v0.x + v1.x + v2.x + v3.x;
                acc.y += v0.y + v1.y + v2.y + v3.y;
                acc.z += v0.z + v1.z + v2.z + v3.z;
                acc.w += v0.w + v1.w + v2.w + v3.w;
            }
            for (; e < end; ++e) {
                int s0 = csr_src[e];
                float4 v0 = X4[(size_t)s0 * 32 + lane];
                acc.x += v0.x; acc.y += v0.y; acc.z += v0.z; acc.w += v0.w;
            }
        }
        *(float4*)&As[rr * 132 + c0] = acc;
    }

    // ---- Phase 2: GEMM As @ W^T ------------------------------------------
    float acc[8][4];
#pragma unroll
    for (int r = 0; r < 8; r++)
#pragma unroll
        for (int c = 0; c < 4; c++) acc[r][c] = 0.0f;

    for (int kc = 0; kc < 128; kc += 32) {
        __syncthreads();   // As ready (kc=0) / previous Ws reads done (kc>0)
#pragma unroll
        for (int i = 0; i < 4; i++) {
            int idx = t + i * 256;
            int k4  = idx & 7;
            int c   = idx >> 3;
            float4 v = *(const float4*)&W[(size_t)c * F + kc + k4 * 4];
            Ws[(k4 * 4 + 0) * 132 + c] = v.x;
            Ws[(k4 * 4 + 1) * 132 + c] = v.y;
            Ws[(k4 * 4 + 2) * 132 + c] = v.z;
            Ws[(k4 * 4 + 3) * 132 + c] = v.w;
        }
        __syncthreads();

#pragma unroll
        for (int k4 = 0; k4 < 8; k4++) {
            float4 a4[8];
#pragma unroll
            for (int r = 0; r < 8; r++)
                a4[r] = *(const float4*)&As[(r0 + r) * 132 + kc + k4 * 4];
            float4 w4[4];
#pragma unroll
            for (int j = 0; j < 4; j++)
                w4[j] = *(const float4*)&Ws[(k4 * 4 + j) * 132 + c0];
#pragma unroll
            for (int r = 0; r < 8; r++) {
                float4 a = a4[r];
                acc[r][0] += a.x * w4[0].x + a.y * w4[1].x + a.z * w4[2].x + a.w * w4[3].x;
                acc[r][1] += a.x * w4[0].y + a.y * w4[1].y + a.z * w4[2].y + a.w * w4[3].y;
                acc[r][2] += a.x * w4[0].z + a.y * w4[1].z + a.z * w4[2].z + a.w * w4[3].z;
                acc[r][3] += a.x * w4[0].w + a.y * w4[1].w + a.z * w4[2].w + a.w * w4[3].w;
            }
        }
    }

    // ---- Epilogue: bias*(deg+1), store, BN-stats partials ----------------
    float4 bv = *(const float4*)&bias[c0];
    float sum[4] = {0.f, 0.f, 0.f, 0.f};
    float ssq[4] = {0.f, 0.f, 0.f, 0.f};
#pragma unroll
    for (int r = 0; r < 8; r++) {
        int grow = row0 + r0 + r;
        if (grow < N_NODES) {
            float scale = (float)(deg[grow] + 1);
            float4 o;
            o.x = acc[r][0] + scale * bv.x;
            o.y = acc[r][1] + scale * bv.y;
            o.z = acc[r][2] + scale * bv.z;
            o.w = acc[r][3] + scale * bv.w;
            *(float4*)&out[(size_t)grow * F + c0] = o;
            sum[0] += o.x; sum[1] += o.y; sum[2] += o.z; sum[3] += o.w;
            ssq[0] += o.x * o.x; ssq[1] += o.y * o.y;
            ssq[2] += o.z * o.z; ssq[3] += o.w * o.w;
        }
    }

    __syncthreads();                 // all As/Ws reads done; reuse As as scratch
    float* red = As;                 // 256 threads * 8 floats = 8 KB
    float* my  = &red[t * 8];
    my[0] = sum[0]; my[1] = sum[1]; my[2] = sum[2]; my[3] = sum[3];
    my[4] = ssq[0]; my[5] = ssq[1]; my[6] = ssq[2]; my[7] = ssq[3];
    __syncthreads();

    if (g == 0) {                    // t = lane < 32
        float a8[8];
#pragma unroll
        for (int j = 0; j < 8; j++) a8[j] = red[lane * 8 + j];
        for (int gg = 1; gg < 8; gg++)
#pragma unroll
            for (int j = 0; j < 8; j++) a8[j] += red[(gg * 32 + lane) * 8 + j];
#pragma unroll
        for (int j = 0; j < 4; j++) {
            unsafeAtomicAdd(&stats[c0 + j],       a8[j]);
            unsafeAtomicAdd(&stats[128 + c0 + j], a8[4 + j]);
        }
    }
}

// ---------------------------------------------------------------------------
// K5: out = relu(gamma*(agg-mean)*rsqrt(var+eps)+beta) + node_feats (in place)
// ---------------------------------------------------------------------------
__global__ __launch_bounds__(256) void finalize_kernel(
    const float* __restrict__ stats,
    const float* __restrict__ gamma,
    const float* __restrict__ beta,
    const float* __restrict__ x,
    float* __restrict__ agg)
{
    __shared__ float s_scale[128];
    __shared__ float s_shift[128];
    const int t = threadIdx.x;
    if (t < 128) {
        const float inv_n = 1.0f / (float)N_NODES;
        float mean = stats[t] * inv_n;
        float var  = stats[128 + t] * inv_n - mean * mean;
        float sc   = gamma[t] * rsqrtf(var + BN_EPS);
        s_scale[t] = sc;
        s_shift[t] = beta[t] - mean * sc;
    }
    __syncthreads();

    const long long total = (long long)N_NODES * F / 4;
    long long i0 = (long long)blockIdx.x * blockDim.x + t;
    for (long long i = i0; i < total; i += (long long)gridDim.x * blockDim.x) {
        int cb = (int)(i & 31) * 4;
        float4 v  = ((const float4*)agg)[i];
        float4 xf = ((const float4*)x)[i];
        float4 o;
        o.x = fmaxf(v.x * s_scale[cb + 0] + s_shift[cb + 0], 0.f) + xf.x;
        o.y = fmaxf(v.y * s_scale[cb + 1] + s_shift[cb + 1], 0.f) + xf.y;
        o.z = fmaxf(v.z * s_scale[cb + 2] + s_shift[cb + 2], 0.f) + xf.z;
        o.w = fmaxf(v.w * s_scale[cb + 3] + s_shift[cb + 3], 0.f) + xf.w;
        ((float4*)agg)[i] = o;
    }
}

// ---------------------------------------------------------------------------
extern "C" void kernel_launch(void* const* d_in, const int* in_sizes, int n_in,
                              void* d_out, int out_size, void* d_ws, size_t ws_size,
                              hipStream_t stream) {
    const float* node_feats = (const float*)d_in[0];
    const float* W          = (const float*)d_in[1];
    const float* b          = (const float*)d_in[2];
    const float* gamma      = (const float*)d_in[3];
    const float* beta       = (const float*)d_in[4];
    const int*   src        = (const int*)d_in[5];
    const int*   dst        = (const int*)d_in[6];

    float* out     = (float*)d_out;
    char*  ws      = (char*)d_ws;
    float* stats   = (float*)(ws + O_STATS);
    int*   deg     = (int*)(ws + O_DEG);
    int*   offsets = (int*)(ws + O_OFF);
    int*   cursor  = (int*)(ws + O_CURSOR);
    int*   csr_src = (int*)(ws + O_CSR);
    int*   bsum    = (int*)(ws + O_BSUM);

    // zero stats + deg
    hipMemsetAsync(d_ws, 0, O_OFF, stream);

    hist_kernel<<<(N_EDGES / 4 + 255) / 256, 256, 0, stream>>>(dst, deg);

    scan_partial<<<SCAN_BLOCKS, 256, 0, stream>>>(deg, bsum);
    scan_bsum<<<1, 256, 0, stream>>>(bsum);
    scan_final<<<SCAN_BLOCKS, 256, 0, stream>>>(deg, bsum, offsets, cursor);

    fill_kernel<<<(N_EDGES / 2 + 255) / 256, 256, 0, stream>>>(src, dst, cursor, csr_src);

    // fused gather + GEMM + stats
    fused_agg_gemm<<<(N_NODES + 63) / 64, 256, 0, stream>>>(
        node_feats, offsets, csr_src, W, b, deg, out, stats);

    finalize_kernel<<<2048, 256, 0, stream>>>(stats, gamma, beta, node_feats, out);
}

// Round 5
// 543.330 us; speedup vs baseline: 1.1836x; 1.1836x over previous
//
#include <hip/hip_runtime.h>

#define N_NODES 100000
#define N_EDGES 1600000
#define F 128
#define BN_EPS 1e-5f
#define SB 512                                   // deg elements per scan block
#define SCAN_BLOCKS ((N_NODES + SB - 1) / SB)    // 196

// Workspace layout (bytes):
//   [0, 1024)            stats: 256 floats (sum, sumsq)
//   [1024, 401024)       deg:     N_NODES ints
//   [401024, 801040)     offsets: N_NODES+1 ints (padded)
//   [801040, 1201040)    cursor:  N_NODES ints
//   [1201040, 7601040)   csr_src: N_EDGES ints
//   [7601040, 7602064)   bsum:    256 ints
//   [7602064, ...)       aggx:    N_NODES*128 floats (gather output)
#define O_STATS   0
#define O_DEG     1024
#define O_OFF     401024
#define O_CURSOR  801040
#define O_CSR     1201040
#define O_BSUM    7601040
#define O_AGGX    7602064

// ---------------------------------------------------------------------------
// K1: histogram of dst -> deg[]   (4 edges/thread, int4 loads)
// ---------------------------------------------------------------------------
__global__ __launch_bounds__(256) void hist_kernel(
    const int* __restrict__ dst, int* __restrict__ deg)
{
    int e = (blockIdx.x * blockDim.x + threadIdx.x) * 4;
    if (e + 3 < N_EDGES) {
        int4 d4 = *(const int4*)&dst[e];
        atomicAdd(&deg[d4.x], 1);
        atomicAdd(&deg[d4.y], 1);
        atomicAdd(&deg[d4.z], 1);
        atomicAdd(&deg[d4.w], 1);
    } else {
        for (; e < N_EDGES; ++e) atomicAdd(&deg[dst[e]], 1);
    }
}

// ---------------------------------------------------------------------------
// K2a: per-block partial sums of deg (512 elems / block)
// ---------------------------------------------------------------------------
__global__ __launch_bounds__(256) void scan_partial(
    const int* __restrict__ deg, int* __restrict__ bsum)
{
    const int t = threadIdx.x;
    const int i0 = blockIdx.x * SB + t * 2;
    int v0 = (i0 < N_NODES)     ? deg[i0]     : 0;
    int v1 = (i0 + 1 < N_NODES) ? deg[i0 + 1] : 0;
    __shared__ int red[256];
    red[t] = v0 + v1;
    __syncthreads();
    for (int d = 128; d > 0; d >>= 1) {
        if (t < d) red[t] += red[t + d];
        __syncthreads();
    }
    if (t == 0) bsum[blockIdx.x] = red[0];
}

// ---------------------------------------------------------------------------
// K2b: single tiny block: exclusive scan of the block sums (in place)
// ---------------------------------------------------------------------------
__global__ __launch_bounds__(256) void scan_bsum(int* __restrict__ bsum)
{
    const int t = threadIdx.x;
    __shared__ int ls[256];
    int v = (t < SCAN_BLOCKS) ? bsum[t] : 0;
    ls[t] = v;
    __syncthreads();
    for (int d = 1; d < 256; d <<= 1) {
        int u = (t >= d) ? ls[t - d] : 0;
        __syncthreads();
        ls[t] += u;
        __syncthreads();
    }
    if (t < SCAN_BLOCKS) bsum[t] = ls[t] - v;    // exclusive base
}

// ---------------------------------------------------------------------------
// K2c: intra-block exclusive scan + base -> offsets, cursor
// ---------------------------------------------------------------------------
__global__ __launch_bounds__(256) void scan_final(
    const int* __restrict__ deg,
    const int* __restrict__ bsum,
    int* __restrict__ offsets,
    int* __restrict__ cursor)
{
    const int t = threadIdx.x;
    const int i0 = blockIdx.x * SB + t * 2;
    int v0 = (i0 < N_NODES)     ? deg[i0]     : 0;
    int v1 = (i0 + 1 < N_NODES) ? deg[i0 + 1] : 0;
    int s = v0 + v1;
    __shared__ int ls[256];
    ls[t] = s;
    __syncthreads();
    for (int d = 1; d < 256; d <<= 1) {
        int u = (t >= d) ? ls[t - d] : 0;
        __syncthreads();
        ls[t] += u;
        __syncthreads();
    }
    int ex = bsum[blockIdx.x] + ls[t] - s;
    if (i0 < N_NODES)     { offsets[i0]     = ex;      cursor[i0]     = ex; }
    if (i0 + 1 < N_NODES) { offsets[i0 + 1] = ex + v0; cursor[i0 + 1] = ex + v0; }
    if (blockIdx.x == gridDim.x - 1 && t == 255) offsets[N_NODES] = N_EDGES;
}

// ---------------------------------------------------------------------------
// K3: bucket fill: csr_src[cursor[dst]++] = src   (2 edges/thread for ILP)
// ---------------------------------------------------------------------------
__global__ __launch_bounds__(256) void fill_kernel(
    const int* __restrict__ src,
    const int* __restrict__ dst,
    int* __restrict__ cursor,
    int* __restrict__ csr_src)
{
    int e = (blockIdx.x * blockDim.x + threadIdx.x) * 2;
    if (e + 1 < N_EDGES) {
        int2 s2 = *(const int2*)&src[e];
        int2 d2 = *(const int2*)&dst[e];
        int p0 = atomicAdd(&cursor[d2.x], 1);
        int p1 = atomicAdd(&cursor[d2.y], 1);
        csr_src[p0] = s2.x;
        csr_src[p1] = s2.y;
    } else if (e < N_EDGES) {
        int pos = atomicAdd(&cursor[dst[e]], 1);
        csr_src[pos] = src[e];
    }
}

// ---------------------------------------------------------------------------
// K4: pull-gather: aggx[v] = X[v] + sum_{e in CSR[v]} X[src[e]]
// 32 lanes per node; lane handles one float4 (4 cols). No LDS, low VGPR ->
// high occupancy; this kernel lives on TLP (lesson from round-4 fusion).
// ---------------------------------------------------------------------------
__global__ __launch_bounds__(256) void gather_kernel(
    const float* __restrict__ X,
    const int* __restrict__ offsets,
    const int* __restrict__ csr_src,
    float* __restrict__ aggx)
{
    int g    = blockIdx.x * 8 + (threadIdx.x >> 5);   // node id
    int lane = threadIdx.x & 31;
    if (g >= N_NODES) return;

    const float4* X4 = (const float4*)X;
    float4 acc = X4[(size_t)g * 32 + lane];           // self loop

    int beg = offsets[g];
    int end = offsets[g + 1];

    int e = beg;
    for (; e + 3 < end; e += 4) {
        int s0 = csr_src[e];
        int s1 = csr_src[e + 1];
        int s2 = csr_src[e + 2];
        int s3 = csr_src[e + 3];
        float4 v0 = X4[(size_t)s0 * 32 + lane];
        float4 v1 = X4[(size_t)s1 * 32 + lane];
        float4 v2 = X4[(size_t)s2 * 32 + lane];
        float4 v3 = X4[(size_t)s3 * 32 + lane];
        acc.x += v0.x + v1.x + v2.x + v3.x;
        acc.y += v0.y + v1.y + v2.y + v3.y;
        acc.z += v0.z + v1.z + v2.z + v3.z;
        acc.w += v0.w + v1.w + v2.w + v3.w;
    }
    for (; e < end; ++e) {
        int s0 = csr_src[e];
        float4 v0 = X4[(size_t)s0 * 32 + lane];
        acc.x += v0.x; acc.y += v0.y; acc.z += v0.z; acc.w += v0.w;
    }
    ((float4*)aggx)[(size_t)g * 32 + lane] = acc;
}

// ---------------------------------------------------------------------------
// K5: out = aggx @ W^T + (deg+1)*b, with BN-stats partials in the epilogue.
// Throughput-bound: occupancy-insensitive, so stats fusion is safe here.
// ---------------------------------------------------------------------------
__global__ __launch_bounds__(256) void gemm_kernel(
    const float* __restrict__ A,     // [N_NODES,128] aggregated feats
    const float* __restrict__ W,     // [128,128] row-major [out][in]
    const float* __restrict__ bias,  // [128]
    const int* __restrict__ deg,     // [N_NODES]
    float* __restrict__ out,
    float* __restrict__ stats)
{
    __shared__ float As[64 * 36];    // 9.2 KB
    __shared__ float Ws[32 * 132];   // 16.9 KB

    const int t   = threadIdx.x;
    const int tc  = t & 31;
    const int tr  = t >> 5;
    const int c0  = tc * 4;
    const int r0  = tr * 8;
    const int row0 = blockIdx.x * 64;

    float acc[8][4];
#pragma unroll
    for (int r = 0; r < 8; r++)
#pragma unroll
        for (int c = 0; c < 4; c++) acc[r][c] = 0.0f;

    for (int kc = 0; kc < 128; kc += 32) {
        __syncthreads();
#pragma unroll
        for (int i = 0; i < 2; i++) {
            int idx = t * 2 + i;
            int r   = idx >> 3;
            int k4  = idx & 7;
            int grow = row0 + r;
            float4 v = make_float4(0.f, 0.f, 0.f, 0.f);
            if (grow < N_NODES)
                v = *(const float4*)&A[(size_t)grow * F + kc + k4 * 4];
            *(float4*)&As[r * 36 + k4 * 4] = v;
        }
#pragma unroll
        for (int i = 0; i < 4; i++) {
            int idx = t + i * 256;
            int k4  = idx & 7;
            int c   = idx >> 3;
            float4 v = *(const float4*)&W[(size_t)c * F + kc + k4 * 4];
            Ws[(k4 * 4 + 0) * 132 + c] = v.x;
            Ws[(k4 * 4 + 1) * 132 + c] = v.y;
            Ws[(k4 * 4 + 2) * 132 + c] = v.z;
            Ws[(k4 * 4 + 3) * 132 + c] = v.w;
        }
        __syncthreads();

#pragma unroll
        for (int k4 = 0; k4 < 8; k4++) {
            float4 a4[8];
#pragma unroll
            for (int r = 0; r < 8; r++)
                a4[r] = *(const float4*)&As[(r0 + r) * 36 + k4 * 4];
            float4 w4[4];
#pragma unroll
            for (int j = 0; j < 4; j++)
                w4[j] = *(const float4*)&Ws[(k4 * 4 + j) * 132 + c0];
#pragma unroll
            for (int r = 0; r < 8; r++) {
                float4 a = a4[r];
                acc[r][0] += a.x * w4[0].x + a.y * w4[1].x + a.z * w4[2].x + a.w * w4[3].x;
                acc[r][1] += a.x * w4[0].y + a.y * w4[1].y + a.z * w4[2].y + a.w * w4[3].y;
                acc[r][2] += a.x * w4[0].z + a.y * w4[1].z + a.z * w4[2].z + a.w * w4[3].z;
                acc[r][3] += a.x * w4[0].w + a.y * w4[1].w + a.z * w4[2].w + a.w * w4[3].w;
            }
        }
    }

    // ---- Epilogue: bias*(deg+1), store, BN-stats partials ----------------
    float4 bv = *(const float4*)&bias[c0];
    float sum[4] = {0.f, 0.f, 0.f, 0.f};
    float ssq[4] = {0.f, 0.f, 0.f, 0.f};
#pragma unroll
    for (int r = 0; r < 8; r++) {
        int grow = row0 + r0 + r;
        if (grow < N_NODES) {
            float scale = (float)(deg[grow] + 1);
            float4 o;
            o.x = acc[r][0] + scale * bv.x;
            o.y = acc[r][1] + scale * bv.y;
            o.z = acc[r][2] + scale * bv.z;
            o.w = acc[r][3] + scale * bv.w;
            *(float4*)&out[(size_t)grow * F + c0] = o;
            sum[0] += o.x; sum[1] += o.y; sum[2] += o.z; sum[3] += o.w;
            ssq[0] += o.x * o.x; ssq[1] += o.y * o.y;
            ssq[2] += o.z * o.z; ssq[3] += o.w * o.w;
        }
    }

    __syncthreads();                 // all Ws/As reads done; reuse Ws as scratch
    float* red = Ws;                 // 256 threads * 8 floats = 8 KB
    float* my  = &red[t * 8];
    my[0] = sum[0]; my[1] = sum[1]; my[2] = sum[2]; my[3] = sum[3];
    my[4] = ssq[0]; my[5] = ssq[1]; my[6] = ssq[2]; my[7] = ssq[3];
    __syncthreads();

    if (tr == 0) {                   // t = tc = lane < 32
        float a8[8];
#pragma unroll
        for (int j = 0; j < 8; j++) a8[j] = red[tc * 8 + j];
        for (int gg = 1; gg < 8; gg++)
#pragma unroll
            for (int j = 0; j < 8; j++) a8[j] += red[(gg * 32 + tc) * 8 + j];
#pragma unroll
        for (int j = 0; j < 4; j++) {
            unsafeAtomicAdd(&stats[c0 + j],       a8[j]);
            unsafeAtomicAdd(&stats[128 + c0 + j], a8[4 + j]);
        }
    }
}

// ---------------------------------------------------------------------------
// K6: out = relu(gamma*(agg-mean)*rsqrt(var+eps)+beta) + node_feats (in place)
// ---------------------------------------------------------------------------
__global__ __launch_bounds__(256) void finalize_kernel(
    const float* __restrict__ stats,
    const float* __restrict__ gamma,
    const float* __restrict__ beta,
    const float* __restrict__ x,
    float* __restrict__ agg)
{
    __shared__ float s_scale[128];
    __shared__ float s_shift[128];
    const int t = threadIdx.x;
    if (t < 128) {
        const float inv_n = 1.0f / (float)N_NODES;
        float mean = stats[t] * inv_n;
        float var  = stats[128 + t] * inv_n - mean * mean;
        float sc   = gamma[t] * rsqrtf(var + BN_EPS);
        s_scale[t] = sc;
        s_shift[t] = beta[t] - mean * sc;
    }
    __syncthreads();

    const long long total = (long long)N_NODES * F / 4;
    long long i0 = (long long)blockIdx.x * blockDim.x + t;
    for (long long i = i0; i < total; i += (long long)gridDim.x * blockDim.x) {
        int cb = (int)(i & 31) * 4;
        float4 v  = ((const float4*)agg)[i];
        float4 xf = ((const float4*)x)[i];
        float4 o;
        o.x = fmaxf(v.x * s_scale[cb + 0] + s_shift[cb + 0], 0.f) + xf.x;
        o.y = fmaxf(v.y * s_scale[cb + 1] + s_shift[cb + 1], 0.f) + xf.y;
        o.z = fmaxf(v.z * s_scale[cb + 2] + s_shift[cb + 2], 0.f) + xf.z;
        o.w = fmaxf(v.w * s_scale[cb + 3] + s_shift[cb + 3], 0.f) + xf.w;
        ((float4*)agg)[i] = o;
    }
}

// ---------------------------------------------------------------------------
extern "C" void kernel_launch(void* const* d_in, const int* in_sizes, int n_in,
                              void* d_out, int out_size, void* d_ws, size_t ws_size,
                              hipStream_t stream) {
    const float* node_feats = (const float*)d_in[0];
    const float* W          = (const float*)d_in[1];
    const float* b          = (const float*)d_in[2];
    const float* gamma      = (const float*)d_in[3];
    const float* beta       = (const float*)d_in[4];
    const int*   src        = (const int*)d_in[5];
    const int*   dst        = (const int*)d_in[6];

    float* out     = (float*)d_out;
    char*  ws      = (char*)d_ws;
    float* stats   = (float*)(ws + O_STATS);
    int*   deg     = (int*)(ws + O_DEG);
    int*   offsets = (int*)(ws + O_OFF);
    int*   cursor  = (int*)(ws + O_CURSOR);
    int*   csr_src = (int*)(ws + O_CSR);
    int*   bsum    = (int*)(ws + O_BSUM);
    float* aggx    = (float*)(ws + O_AGGX);

    // zero stats + deg
    hipMemsetAsync(d_ws, 0, O_OFF, stream);

    hist_kernel<<<(N_EDGES / 4 + 255) / 256, 256, 0, stream>>>(dst, deg);

    scan_partial<<<SCAN_BLOCKS, 256, 0, stream>>>(deg, bsum);
    scan_bsum<<<1, 256, 0, stream>>>(bsum);
    scan_final<<<SCAN_BLOCKS, 256, 0, stream>>>(deg, bsum, offsets, cursor);

    fill_kernel<<<(N_EDGES / 2 + 255) / 256, 256, 0, stream>>>(src, dst, cursor, csr_src);

    // aggregate raw features into ws (standalone, high occupancy)
    gather_kernel<<<(N_NODES + 7) / 8, 256, 0, stream>>>(node_feats, offsets, csr_src, aggx);

    // project + BN stats
    gemm_kernel<<<(N_NODES + 63) / 64, 256, 0, stream>>>(aggx, W, b, deg, out, stats);

    finalize_kernel<<<2048, 256, 0, stream>>>(stats, gamma, beta, node_feats, out);
}

// Round 6
// 415.024 us; speedup vs baseline: 1.5495x; 1.3092x over previous
//
#include <hip/hip_runtime.h>

#define N_NODES 100000
#define N_EDGES 1600000
#define F 128
#define BN_EPS 1e-5f
#define SB 512                                   // deg elements per scan block
#define SCAN_BLOCKS ((N_NODES + SB - 1) / SB)    // 196

// Workspace layout (bytes):
//   [0, 1024)            stats: 256 floats (sum, sumsq)
//   [1024, 401024)       deg:     N_NODES ints
//   [401024, 801040)     offsets: N_NODES+1 ints (padded)
//   [801040, 1201040)    cursor:  N_NODES ints
//   [1201040, 7601040)   csr_src: N_EDGES ints
//   [7601040, 7602064)   bsum:    256 ints
//   [7602064, 33202064)  aggb:    N_NODES*128 bf16 (gather output)
//   [33202064, 33234832) Wb:      128*128 bf16
#define O_STATS   0
#define O_DEG     1024
#define O_OFF     401024
#define O_CURSOR  801040
#define O_CSR     1201040
#define O_BSUM    7601040
#define O_AGGB    7602064
#define O_WB      33202064

typedef __attribute__((ext_vector_type(8))) short bf16x8;
typedef __attribute__((ext_vector_type(4))) float f32x4;

__device__ __forceinline__ unsigned short f2bf(float f) {
    union { float f; unsigned u; } v; v.f = f;
    unsigned u = v.u;
    unsigned r = u + 0x7FFFu + ((u >> 16) & 1u);   // round-to-nearest-even
    return (unsigned short)(r >> 16);
}

// ---------------------------------------------------------------------------
// K0: convert W to bf16
// ---------------------------------------------------------------------------
__global__ __launch_bounds__(256) void convert_w(
    const float* __restrict__ W, unsigned short* __restrict__ Wb)
{
    int i = blockIdx.x * blockDim.x + threadIdx.x;   // 64 blocks * 256 = 16384
    Wb[i] = f2bf(W[i]);
}

// ---------------------------------------------------------------------------
// K1: histogram of dst -> deg[]   (4 edges/thread, int4 loads)
// ---------------------------------------------------------------------------
__global__ __launch_bounds__(256) void hist_kernel(
    const int* __restrict__ dst, int* __restrict__ deg)
{
    int e = (blockIdx.x * blockDim.x + threadIdx.x) * 4;
    if (e + 3 < N_EDGES) {
        int4 d4 = *(const int4*)&dst[e];
        atomicAdd(&deg[d4.x], 1);
        atomicAdd(&deg[d4.y], 1);
        atomicAdd(&deg[d4.z], 1);
        atomicAdd(&deg[d4.w], 1);
    } else {
        for (; e < N_EDGES; ++e) atomicAdd(&deg[dst[e]], 1);
    }
}

// ---------------------------------------------------------------------------
// K2a: per-block partial sums of deg (512 elems / block)
// ---------------------------------------------------------------------------
__global__ __launch_bounds__(256) void scan_partial(
    const int* __restrict__ deg, int* __restrict__ bsum)
{
    const int t = threadIdx.x;
    const int i0 = blockIdx.x * SB + t * 2;
    int v0 = (i0 < N_NODES)     ? deg[i0]     : 0;
    int v1 = (i0 + 1 < N_NODES) ? deg[i0 + 1] : 0;
    __shared__ int red[256];
    red[t] = v0 + v1;
    __syncthreads();
    for (int d = 128; d > 0; d >>= 1) {
        if (t < d) red[t] += red[t + d];
        __syncthreads();
    }
    if (t == 0) bsum[blockIdx.x] = red[0];
}

// ---------------------------------------------------------------------------
// K2b: single tiny block: exclusive scan of the block sums (in place)
// ---------------------------------------------------------------------------
__global__ __launch_bounds__(256) void scan_bsum(int* __restrict__ bsum)
{
    const int t = threadIdx.x;
    __shared__ int ls[256];
    int v = (t < SCAN_BLOCKS) ? bsum[t] : 0;
    ls[t] = v;
    __syncthreads();
    for (int d = 1; d < 256; d <<= 1) {
        int u = (t >= d) ? ls[t - d] : 0;
        __syncthreads();
        ls[t] += u;
        __syncthreads();
    }
    if (t < SCAN_BLOCKS) bsum[t] = ls[t] - v;    // exclusive base
}

// ---------------------------------------------------------------------------
// K2c: intra-block exclusive scan + base -> offsets, cursor
// ---------------------------------------------------------------------------
__global__ __launch_bounds__(256) void scan_final(
    const int* __restrict__ deg,
    const int* __restrict__ bsum,
    int* __restrict__ offsets,
    int* __restrict__ cursor)
{
    const int t = threadIdx.x;
    const int i0 = blockIdx.x * SB + t * 2;
    int v0 = (i0 < N_NODES)     ? deg[i0]     : 0;
    int v1 = (i0 + 1 < N_NODES) ? deg[i0 + 1] : 0;
    int s = v0 + v1;
    __shared__ int ls[256];
    ls[t] = s;
    __syncthreads();
    for (int d = 1; d < 256; d <<= 1) {
        int u = (t >= d) ? ls[t - d] : 0;
        __syncthreads();
        ls[t] += u;
        __syncthreads();
    }
    int ex = bsum[blockIdx.x] + ls[t] - s;
    if (i0 < N_NODES)     { offsets[i0]     = ex;      cursor[i0]     = ex; }
    if (i0 + 1 < N_NODES) { offsets[i0 + 1] = ex + v0; cursor[i0 + 1] = ex + v0; }
    if (blockIdx.x == gridDim.x - 1 && t == 255) offsets[N_NODES] = N_EDGES;
}

// ---------------------------------------------------------------------------
// K3: bucket fill: csr_src[cursor[dst]++] = src   (2 edges/thread for ILP)
// ---------------------------------------------------------------------------
__global__ __launch_bounds__(256) void fill_kernel(
    const int* __restrict__ src,
    const int* __restrict__ dst,
    int* __restrict__ cursor,
    int* __restrict__ csr_src)
{
    int e = (blockIdx.x * blockDim.x + threadIdx.x) * 2;
    if (e + 1 < N_EDGES) {
        int2 s2 = *(const int2*)&src[e];
        int2 d2 = *(const int2*)&dst[e];
        int p0 = atomicAdd(&cursor[d2.x], 1);
        int p1 = atomicAdd(&cursor[d2.y], 1);
        csr_src[p0] = s2.x;
        csr_src[p1] = s2.y;
    } else if (e < N_EDGES) {
        int pos = atomicAdd(&cursor[dst[e]], 1);
        csr_src[pos] = src[e];
    }
}

// ---------------------------------------------------------------------------
// K4: pull-gather: aggb[v] = bf16( X[v] + sum_{e in CSR[v]} X[src[e]] )
// fp32 accumulate, bf16 store. No LDS, low VGPR -> high occupancy (TLP).
// ---------------------------------------------------------------------------
__global__ __launch_bounds__(256) void gather_kernel(
    const float* __restrict__ X,
    const int* __restrict__ offsets,
    const int* __restrict__ csr_src,
    unsigned short* __restrict__ aggb)
{
    int g    = blockIdx.x * 8 + (threadIdx.x >> 5);   // node id
    int lane = threadIdx.x & 31;
    if (g >= N_NODES) return;

    const float4* X4 = (const float4*)X;
    float4 acc = X4[(size_t)g * 32 + lane];           // self loop

    int beg = offsets[g];
    int end = offsets[g + 1];

    int e = beg;
    for (; e + 3 < end; e += 4) {
        int s0 = csr_src[e];
        int s1 = csr_src[e + 1];
        int s2 = csr_src[e + 2];
        int s3 = csr_src[e + 3];
        float4 v0 = X4[(size_t)s0 * 32 + lane];
        float4 v1 = X4[(size_t)s1 * 32 + lane];
        float4 v2 = X4[(size_t)s2 * 32 + lane];
        float4 v3 = X4[(size_t)s3 * 32 + lane];
        acc.x += v0.x + v1.x + v2.x + v3.x;
        acc.y += v0.y + v1.y + v2.y + v3.y;
        acc.z += v0.z + v1.z + v2.z + v3.z;
        acc.w += v0.w + v1.w + v2.w + v3.w;
    }
    for (; e < end; ++e) {
        int s0 = csr_src[e];
        float4 v0 = X4[(size_t)s0 * 32 + lane];
        acc.x += v0.x; acc.y += v0.y; acc.z += v0.z; acc.w += v0.w;
    }
    ushort4 o;
    o.x = f2bf(acc.x); o.y = f2bf(acc.y); o.z = f2bf(acc.z); o.w = f2bf(acc.w);
    ((ushort4*)aggb)[(size_t)g * 32 + lane] = o;
}

// ---------------------------------------------------------------------------
// K5: MFMA GEMM: out = aggb @ Wb^T + (deg+1)*b, BN-stats in epilogue.
// 4 waves/block, wave = 16 rows x 128 cols. mfma_f32_16x16x32_bf16.
// A frag: lane l -> A[l&15][(l>>4)*8 + j]; B frag: lane l -> B[(l>>4)*8+j][l&15]
// with B[k][n] = W[n][k] (W layout is already B^T). D: row=(l>>4)*4+r, col=l&15.
// ---------------------------------------------------------------------------
__global__ __launch_bounds__(256) void gemm_mfma(
    const unsigned short* __restrict__ Ab,   // [N,128] bf16
    const unsigned short* __restrict__ Wb,   // [128,128] bf16 [out][in]
    const float* __restrict__ bias,          // [128] fp32
    const int* __restrict__ deg,
    float* __restrict__ out,
    float* __restrict__ stats)
{
    const int t   = threadIdx.x;
    const int w   = t >> 6;          // wave 0..3
    const int l   = t & 63;
    const int l16 = l & 15;
    const int lk  = l >> 4;          // 0..3 (k-group / row-group)
    const int rowbase = blockIdx.x * 64 + w * 16;

    // A fragment row for this lane
    int arow = rowbase + l16;
    int arow_c = (arow < N_NODES) ? arow : 0;    // clamp; garbage rows masked at store

    f32x4 acc[8];
#pragma unroll
    for (int nt = 0; nt < 8; nt++) acc[nt] = (f32x4){0.f, 0.f, 0.f, 0.f};

    const bf16x8* A8 = (const bf16x8*)Ab;        // row*16 + k/8
    const bf16x8* W8 = (const bf16x8*)Wb;

#pragma unroll
    for (int ks = 0; ks < 4; ks++) {             // K step of 32
        bf16x8 a = A8[(size_t)arow_c * 16 + ks * 4 + lk];
#pragma unroll
        for (int nt = 0; nt < 8; nt++) {
            int col = nt * 16 + l16;
            bf16x8 b = W8[(size_t)col * 16 + ks * 4 + lk];
            acc[nt] = __builtin_amdgcn_mfma_f32_16x16x32_bf16(a, b, acc[nt], 0, 0, 0);
        }
    }

    // ---- Epilogue: bias*(deg+1), store, BN stats --------------------------
    float bv[8];
#pragma unroll
    for (int nt = 0; nt < 8; nt++) bv[nt] = bias[nt * 16 + l16];

    float sums[8], ssqs[8];
#pragma unroll
    for (int nt = 0; nt < 8; nt++) { sums[nt] = 0.f; ssqs[nt] = 0.f; }

    const int orow = rowbase + lk * 4;
#pragma unroll
    for (int r = 0; r < 4; r++) {
        int row = orow + r;
        if (row < N_NODES) {
            float scale = (float)(deg[row] + 1);
#pragma unroll
            for (int nt = 0; nt < 8; nt++) {
                float o = acc[nt][r] + scale * bv[nt];
                out[(size_t)row * F + nt * 16 + l16] = o;
                sums[nt] += o;
                ssqs[nt] += o * o;
            }
        }
    }

    // reduce the 4 row-groups (lanes l, l^16, l^32) -> col totals per wave
#pragma unroll
    for (int nt = 0; nt < 8; nt++) {
        sums[nt] += __shfl_xor(sums[nt], 16);
        sums[nt] += __shfl_xor(sums[nt], 32);
        ssqs[nt] += __shfl_xor(ssqs[nt], 16);
        ssqs[nt] += __shfl_xor(ssqs[nt], 32);
    }

    __shared__ float red0[128];
    __shared__ float red1[128];
    if (t < 128) { red0[t] = 0.f; red1[t] = 0.f; }
    __syncthreads();
    if (lk == 0) {                   // 16 lanes per wave hold totals
#pragma unroll
        for (int nt = 0; nt < 8; nt++) {
            int col = nt * 16 + l16;
            atomicAdd(&red0[col], sums[nt]);
            atomicAdd(&red1[col], ssqs[nt]);
        }
    }
    __syncthreads();
    if (t < 128) {
        unsafeAtomicAdd(&stats[t],       red0[t]);
        unsafeAtomicAdd(&stats[128 + t], red1[t]);
    }
}

// ---------------------------------------------------------------------------
// K6: out = relu(gamma*(agg-mean)*rsqrt(var+eps)+beta) + node_feats (in place)
// ---------------------------------------------------------------------------
__global__ __launch_bounds__(256) void finalize_kernel(
    const float* __restrict__ stats,
    const float* __restrict__ gamma,
    const float* __restrict__ beta,
    const float* __restrict__ x,
    float* __restrict__ agg)
{
    __shared__ float s_scale[128];
    __shared__ float s_shift[128];
    const int t = threadIdx.x;
    if (t < 128) {
        const float inv_n = 1.0f / (float)N_NODES;
        float mean = stats[t] * inv_n;
        float var  = stats[128 + t] * inv_n - mean * mean;
        float sc   = gamma[t] * rsqrtf(var + BN_EPS);
        s_scale[t] = sc;
        s_shift[t] = beta[t] - mean * sc;
    }
    __syncthreads();

    const long long total = (long long)N_NODES * F / 4;
    long long i0 = (long long)blockIdx.x * blockDim.x + t;
    for (long long i = i0; i < total; i += (long long)gridDim.x * blockDim.x) {
        int cb = (int)(i & 31) * 4;
        float4 v  = ((const float4*)agg)[i];
        float4 xf = ((const float4*)x)[i];
        float4 o;
        o.x = fmaxf(v.x * s_scale[cb + 0] + s_shift[cb + 0], 0.f) + xf.x;
        o.y = fmaxf(v.y * s_scale[cb + 1] + s_shift[cb + 1], 0.f) + xf.y;
        o.z = fmaxf(v.z * s_scale[cb + 2] + s_shift[cb + 2], 0.f) + xf.z;
        o.w = fmaxf(v.w * s_scale[cb + 3] + s_shift[cb + 3], 0.f) + xf.w;
        ((float4*)agg)[i] = o;
    }
}

// ---------------------------------------------------------------------------
extern "C" void kernel_launch(void* const* d_in, const int* in_sizes, int n_in,
                              void* d_out, int out_size, void* d_ws, size_t ws_size,
                              hipStream_t stream) {
    const float* node_feats = (const float*)d_in[0];
    const float* W          = (const float*)d_in[1];
    const float* b          = (const float*)d_in[2];
    const float* gamma      = (const float*)d_in[3];
    const float* beta       = (const float*)d_in[4];
    const int*   src        = (const int*)d_in[5];
    const int*   dst        = (const int*)d_in[6];

    float* out     = (float*)d_out;
    char*  ws      = (char*)d_ws;
    float* stats   = (float*)(ws + O_STATS);
    int*   deg     = (int*)(ws + O_DEG);
    int*   offsets = (int*)(ws + O_OFF);
    int*   cursor  = (int*)(ws + O_CURSOR);
    int*   csr_src = (int*)(ws + O_CSR);
    int*   bsum    = (int*)(ws + O_BSUM);
    unsigned short* aggb = (unsigned short*)(ws + O_AGGB);
    unsigned short* Wb   = (unsigned short*)(ws + O_WB);

    // zero stats + deg
    hipMemsetAsync(d_ws, 0, O_OFF, stream);

    convert_w<<<64, 256, 0, stream>>>(W, Wb);

    hist_kernel<<<(N_EDGES / 4 + 255) / 256, 256, 0, stream>>>(dst, deg);

    scan_partial<<<SCAN_BLOCKS, 256, 0, stream>>>(deg, bsum);
    scan_bsum<<<1, 256, 0, stream>>>(bsum);
    scan_final<<<SCAN_BLOCKS, 256, 0, stream>>>(deg, bsum, offsets, cursor);

    fill_kernel<<<(N_EDGES / 2 + 255) / 256, 256, 0, stream>>>(src, dst, cursor, csr_src);

    // aggregate raw features into ws as bf16 (standalone, high occupancy)
    gather_kernel<<<(N_NODES + 7) / 8, 256, 0, stream>>>(node_feats, offsets, csr_src, aggb);

    // MFMA projection + BN stats
    gemm_mfma<<<(N_NODES + 63) / 64, 256, 0, stream>>>(aggb, Wb, b, deg, out, stats);

    finalize_kernel<<<2048, 256, 0, stream>>>(stats, gamma, beta, node_feats, out);
}

// Round 8
// 339.622 us; speedup vs baseline: 1.8935x; 1.2220x over previous
//
#include <hip/hip_runtime.h>

#define N_NODES 100000
#define N_EDGES 1600000
#define F 128
#define BN_EPS 1e-5f
#define NB 391                        // node buckets of 256: ceil(100000/256)

// Workspace layout (bytes), all 64-aligned, NO overlaps (R7 bug: offsets
// [429248, 829252) overlapped csr_src at 829248 -> one-element corruption):
//   [0, 1024)              stats: 256 floats (sum, sumsq)
//   [1024, 2592)           bcnt:  392 ints (bucket histogram)     } memset 0
//   [2592, 4160)           bbase: 392 ints (bucket exclusive scan)
//   [4160, 29184)          bcursor: 391 ints padded to 64B (idx*16)
//   [29184, 429184)        deg:     N_NODES ints
//   [429248, 829252)       offsets: N_NODES+1 ints
//   [829312, 7229312)      csr_src: N_EDGES ints
//   [7229376, 7262144)     Wb:      128*128 bf16
//   [7262144, 32862144)    aggb:    N_NODES*128 bf16 (gather output)
//                          binned (N_EDGES ints, 6.4MB) ALIASES aggb region
#define O_STATS   0
#define O_BCNT    1024
#define O_BBASE   2592
#define O_BCUR    4160
#define O_DEG     29184
#define O_OFF     429248
#define O_CSR     829312
#define O_WB      7229376
#define O_AGGB    7262144

typedef __attribute__((ext_vector_type(8))) short bf16x8;
typedef __attribute__((ext_vector_type(4))) float f32x4;

__device__ __forceinline__ unsigned short f2bf(float f) {
    union { float f; unsigned u; } v; v.f = f;
    unsigned u = v.u;
    unsigned r = u + 0x7FFFu + ((u >> 16) & 1u);   // round-to-nearest-even
    return (unsigned short)(r >> 16);
}

// ---------------------------------------------------------------------------
// K0: convert W to bf16
// ---------------------------------------------------------------------------
__global__ __launch_bounds__(256) void convert_w(
    const float* __restrict__ W, unsigned short* __restrict__ Wb)
{
    int i = blockIdx.x * blockDim.x + threadIdx.x;
    Wb[i] = f2bf(W[i]);
}

// ---------------------------------------------------------------------------
// K1: bucket histogram of dst>>8, LDS-preaggregated (8 edges/thread)
// ---------------------------------------------------------------------------
__global__ __launch_bounds__(256) void bucket_hist(
    const int* __restrict__ dst, int* __restrict__ bcnt)
{
    __shared__ int h[NB];
    const int t = threadIdx.x;
    for (int i = t; i < NB; i += 256) h[i] = 0;
    __syncthreads();

    int e = (blockIdx.x * blockDim.x + t) * 8;
    if (e + 7 < N_EDGES) {
        int4 a = *(const int4*)&dst[e];
        int4 b = *(const int4*)&dst[e + 4];
        atomicAdd(&h[a.x >> 8], 1); atomicAdd(&h[a.y >> 8], 1);
        atomicAdd(&h[a.z >> 8], 1); atomicAdd(&h[a.w >> 8], 1);
        atomicAdd(&h[b.x >> 8], 1); atomicAdd(&h[b.y >> 8], 1);
        atomicAdd(&h[b.z >> 8], 1); atomicAdd(&h[b.w >> 8], 1);
    } else {
        for (; e < N_EDGES; ++e) atomicAdd(&h[dst[e] >> 8], 1);
    }
    __syncthreads();
    for (int i = t; i < NB; i += 256) {
        int v = h[i];
        if (v) atomicAdd(&bcnt[i], v);
    }
}

// ---------------------------------------------------------------------------
// K2: single block: exclusive scan of 391 bucket counts -> bbase, bcursor
// ---------------------------------------------------------------------------
__global__ __launch_bounds__(512) void bucket_scan(
    const int* __restrict__ bcnt,
    int* __restrict__ bbase,
    int* __restrict__ bcursor)
{
    const int t = threadIdx.x;
    __shared__ int ls[512];
    int v = (t < NB) ? bcnt[t] : 0;
    ls[t] = v;
    __syncthreads();
    for (int d = 1; d < 512; d <<= 1) {
        int u = (t >= d) ? ls[t - d] : 0;
        __syncthreads();
        ls[t] += u;
        __syncthreads();
    }
    if (t < NB) {
        int ex = ls[t] - v;
        bbase[t] = ex;
        bcursor[t * 16] = ex;        // 64B-padded cursor
    }
    if (t == NB - 1) bbase[NB] = ls[t];   // = N_EDGES
}

// ---------------------------------------------------------------------------
// K3: bin edges: binned[cursor[dst>>8]++] = (dst&255)<<17 | src
// 391 line-padded cursors; writes cluster at 391 dense frontiers.
// ---------------------------------------------------------------------------
__global__ __launch_bounds__(256) void bin_fill(
    const int* __restrict__ src,
    const int* __restrict__ dst,
    int* __restrict__ bcursor,
    int* __restrict__ binned)
{
    int e = (blockIdx.x * blockDim.x + threadIdx.x) * 4;
    if (e + 3 < N_EDGES) {
        int4 s4 = *(const int4*)&src[e];
        int4 d4 = *(const int4*)&dst[e];
        int p0 = atomicAdd(&bcursor[(d4.x >> 8) * 16], 1);
        int p1 = atomicAdd(&bcursor[(d4.y >> 8) * 16], 1);
        int p2 = atomicAdd(&bcursor[(d4.z >> 8) * 16], 1);
        int p3 = atomicAdd(&bcursor[(d4.w >> 8) * 16], 1);
        binned[p0] = ((d4.x & 255) << 17) | s4.x;
        binned[p1] = ((d4.y & 255) << 17) | s4.y;
        binned[p2] = ((d4.z & 255) << 17) | s4.z;
        binned[p3] = ((d4.w & 255) << 17) | s4.w;
    } else {
        for (; e < N_EDGES; ++e) {
            int d = dst[e];
            int p = atomicAdd(&bcursor[(d >> 8) * 16], 1);
            binned[p] = ((d & 255) << 17) | src[e];
        }
    }
}

// ---------------------------------------------------------------------------
// K4: per-bucket CSR build. One block per bucket (256 nodes).
// Counts per node in LDS, LDS scan -> offsets/deg (no global per-node scan),
// then scatters src into the bucket's private csr range (L2-resident).
// ---------------------------------------------------------------------------
__global__ __launch_bounds__(256) void csr_build(
    const int* __restrict__ binned,
    const int* __restrict__ bbase,
    int* __restrict__ offsets,
    int* __restrict__ deg,
    int* __restrict__ csr_src)
{
    const int b   = blockIdx.x;
    const int t   = threadIdx.x;
    const int beg = bbase[b];
    const int end = bbase[b + 1];
    const int nb0 = b * 256;

    __shared__ int cnt[256];
    __shared__ int ls[256];
    __shared__ int cur[256];
    cnt[t] = 0;
    __syncthreads();

    for (int i = beg + t; i < end; i += 256)
        atomicAdd(&cnt[binned[i] >> 17], 1);
    __syncthreads();

    int v = cnt[t];
    ls[t] = v;
    __syncthreads();
    for (int d = 1; d < 256; d <<= 1) {
        int u = (t >= d) ? ls[t - d] : 0;
        __syncthreads();
        ls[t] += u;
        __syncthreads();
    }
    int ex = beg + ls[t] - v;        // global exclusive offset for node nb0+t
    cur[t] = ex;
    int node = nb0 + t;
    if (node < N_NODES) {
        offsets[node] = ex;
        deg[node]     = v;
    }
    if (b == NB - 1 && t == 0) offsets[N_NODES] = N_EDGES;
    __syncthreads();

    for (int i = beg + t; i < end; i += 256) {
        int w   = binned[i];
        int pos = atomicAdd(&cur[w >> 17], 1);
        csr_src[pos] = w & 0x1FFFF;
    }
}

// ---------------------------------------------------------------------------
// K5: pull-gather: aggb[v] = bf16( X[v] + sum_{e in CSR[v]} X[src[e]] )
// fp32 accumulate, bf16 store. No LDS, low VGPR -> high occupancy (TLP).
// ---------------------------------------------------------------------------
__global__ __launch_bounds__(256) void gather_kernel(
    const float* __restrict__ X,
    const int* __restrict__ offsets,
    const int* __restrict__ csr_src,
    unsigned short* __restrict__ aggb)
{
    int g    = blockIdx.x * 8 + (threadIdx.x >> 5);   // node id
    int lane = threadIdx.x & 31;
    if (g >= N_NODES) return;

    const float4* X4 = (const float4*)X;
    float4 acc = X4[(size_t)g * 32 + lane];           // self loop

    int beg = offsets[g];
    int end = offsets[g + 1];

    int e = beg;
    for (; e + 3 < end; e += 4) {
        int s0 = csr_src[e];
        int s1 = csr_src[e + 1];
        int s2 = csr_src[e + 2];
        int s3 = csr_src[e + 3];
        float4 v0 = X4[(size_t)s0 * 32 + lane];
        float4 v1 = X4[(size_t)s1 * 32 + lane];
        float4 v2 = X4[(size_t)s2 * 32 + lane];
        float4 v3 = X4[(size_t)s3 * 32 + lane];
        acc.x += v0.x + v1.x + v2.x + v3.x;
        acc.y += v0.y + v1.y + v2.y + v3.y;
        acc.z += v0.z + v1.z + v2.z + v3.z;
        acc.w += v0.w + v1.w + v2.w + v3.w;
    }
    for (; e < end; ++e) {
        int s0 = csr_src[e];
        float4 v0 = X4[(size_t)s0 * 32 + lane];
        acc.x += v0.x; acc.y += v0.y; acc.z += v0.z; acc.w += v0.w;
    }
    ushort4 o;
    o.x = f2bf(acc.x); o.y = f2bf(acc.y); o.z = f2bf(acc.z); o.w = f2bf(acc.w);
    ((ushort4*)aggb)[(size_t)g * 32 + lane] = o;
}

// ---------------------------------------------------------------------------
// K6: MFMA GEMM: out = aggb @ Wb^T + (deg+1)*b, BN-stats in epilogue.
// 4 waves/block, wave = 16 rows x 128 cols. mfma_f32_16x16x32_bf16.
// ---------------------------------------------------------------------------
__global__ __launch_bounds__(256) void gemm_mfma(
    const unsigned short* __restrict__ Ab,   // [N,128] bf16
    const unsigned short* __restrict__ Wb,   // [128,128] bf16 [out][in]
    const float* __restrict__ bias,          // [128] fp32
    const int* __restrict__ deg,
    float* __restrict__ out,
    float* __restrict__ stats)
{
    const int t   = threadIdx.x;
    const int w   = t >> 6;          // wave 0..3
    const int l   = t & 63;
    const int l16 = l & 15;
    const int lk  = l >> 4;          // 0..3 (k-group / row-group)
    const int rowbase = blockIdx.x * 64 + w * 16;

    int arow = rowbase + l16;
    int arow_c = (arow < N_NODES) ? arow : 0;

    f32x4 acc[8];
#pragma unroll
    for (int nt = 0; nt < 8; nt++) acc[nt] = (f32x4){0.f, 0.f, 0.f, 0.f};

    const bf16x8* A8 = (const bf16x8*)Ab;
    const bf16x8* W8 = (const bf16x8*)Wb;

#pragma unroll
    for (int ks = 0; ks < 4; ks++) {
        bf16x8 a = A8[(size_t)arow_c * 16 + ks * 4 + lk];
#pragma unroll
        for (int nt = 0; nt < 8; nt++) {
            int col = nt * 16 + l16;
            bf16x8 b = W8[(size_t)col * 16 + ks * 4 + lk];
            acc[nt] = __builtin_amdgcn_mfma_f32_16x16x32_bf16(a, b, acc[nt], 0, 0, 0);
        }
    }

    float bv[8];
#pragma unroll
    for (int nt = 0; nt < 8; nt++) bv[nt] = bias[nt * 16 + l16];

    float sums[8], ssqs[8];
#pragma unroll
    for (int nt = 0; nt < 8; nt++) { sums[nt] = 0.f; ssqs[nt] = 0.f; }

    const int orow = rowbase + lk * 4;
#pragma unroll
    for (int r = 0; r < 4; r++) {
        int row = orow + r;
        if (row < N_NODES) {
            float scale = (float)(deg[row] + 1);
#pragma unroll
            for (int nt = 0; nt < 8; nt++) {
                float o = acc[nt][r] + scale * bv[nt];
                out[(size_t)row * F + nt * 16 + l16] = o;
                sums[nt] += o;
                ssqs[nt] += o * o;
            }
        }
    }

#pragma unroll
    for (int nt = 0; nt < 8; nt++) {
        sums[nt] += __shfl_xor(sums[nt], 16);
        sums[nt] += __shfl_xor(sums[nt], 32);
        ssqs[nt] += __shfl_xor(ssqs[nt], 16);
        ssqs[nt] += __shfl_xor(ssqs[nt], 32);
    }

    __shared__ float red0[128];
    __shared__ float red1[128];
    if (t < 128) { red0[t] = 0.f; red1[t] = 0.f; }
    __syncthreads();
    if (lk == 0) {
#pragma unroll
        for (int nt = 0; nt < 8; nt++) {
            int col = nt * 16 + l16;
            atomicAdd(&red0[col], sums[nt]);
            atomicAdd(&red1[col], ssqs[nt]);
        }
    }
    __syncthreads();
    if (t < 128) {
        unsafeAtomicAdd(&stats[t],       red0[t]);
        unsafeAtomicAdd(&stats[128 + t], red1[t]);
    }
}

// ---------------------------------------------------------------------------
// K7: out = relu(gamma*(agg-mean)*rsqrt(var+eps)+beta) + node_feats (in place)
// ---------------------------------------------------------------------------
__global__ __launch_bounds__(256) void finalize_kernel(
    const float* __restrict__ stats,
    const float* __restrict__ gamma,
    const float* __restrict__ beta,
    const float* __restrict__ x,
    float* __restrict__ agg)
{
    __shared__ float s_scale[128];
    __shared__ float s_shift[128];
    const int t = threadIdx.x;
    if (t < 128) {
        const float inv_n = 1.0f / (float)N_NODES;
        float mean = stats[t] * inv_n;
        float var  = stats[128 + t] * inv_n - mean * mean;
        float sc   = gamma[t] * rsqrtf(var + BN_EPS);
        s_scale[t] = sc;
        s_shift[t] = beta[t] - mean * sc;
    }
    __syncthreads();

    const long long total = (long long)N_NODES * F / 4;
    long long i0 = (long long)blockIdx.x * blockDim.x + t;
    for (long long i = i0; i < total; i += (long long)gridDim.x * blockDim.x) {
        int cb = (int)(i & 31) * 4;
        float4 v  = ((const float4*)agg)[i];
        float4 xf = ((const float4*)x)[i];
        float4 o;
        o.x = fmaxf(v.x * s_scale[cb + 0] + s_shift[cb + 0], 0.f) + xf.x;
        o.y = fmaxf(v.y * s_scale[cb + 1] + s_shift[cb + 1], 0.f) + xf.y;
        o.z = fmaxf(v.z * s_scale[cb + 2] + s_shift[cb + 2], 0.f) + xf.z;
        o.w = fmaxf(v.w * s_scale[cb + 3] + s_shift[cb + 3], 0.f) + xf.w;
        ((float4*)agg)[i] = o;
    }
}

// ---------------------------------------------------------------------------
extern "C" void kernel_launch(void* const* d_in, const int* in_sizes, int n_in,
                              void* d_out, int out_size, void* d_ws, size_t ws_size,
                              hipStream_t stream) {
    const float* node_feats = (const float*)d_in[0];
    const float* W          = (const float*)d_in[1];
    const float* b          = (const float*)d_in[2];
    const float* gamma      = (const float*)d_in[3];
    const float* beta       = (const float*)d_in[4];
    const int*   src        = (const int*)d_in[5];
    const int*   dst        = (const int*)d_in[6];

    float* out     = (float*)d_out;
    char*  ws      = (char*)d_ws;
    float* stats   = (float*)(ws + O_STATS);
    int*   bcnt    = (int*)(ws + O_BCNT);
    int*   bbase   = (int*)(ws + O_BBASE);
    int*   bcursor = (int*)(ws + O_BCUR);
    int*   deg     = (int*)(ws + O_DEG);
    int*   offsets = (int*)(ws + O_OFF);
    int*   csr_src = (int*)(ws + O_CSR);
    unsigned short* Wb   = (unsigned short*)(ws + O_WB);
    unsigned short* aggb = (unsigned short*)(ws + O_AGGB);
    int*   binned  = (int*)(ws + O_AGGB);   // aliases aggb (dead before gather)

    // zero stats + bcnt
    hipMemsetAsync(d_ws, 0, O_BBASE, stream);

    convert_w<<<64, 256, 0, stream>>>(W, Wb);

    bucket_hist<<<(N_EDGES / 8 + 255) / 256, 256, 0, stream>>>(dst, bcnt);
    bucket_scan<<<1, 512, 0, stream>>>(bcnt, bbase, bcursor);
    bin_fill<<<(N_EDGES / 4 + 255) / 256, 256, 0, stream>>>(src, dst, bcursor, binned);
    csr_build<<<NB, 256, 0, stream>>>(binned, bbase, offsets, deg, csr_src);

    gather_kernel<<<(N_NODES + 7) / 8, 256, 0, stream>>>(node_feats, offsets, csr_src, aggb);

    gemm_mfma<<<(N_NODES + 63) / 64, 256, 0, stream>>>(aggb, Wb, b, deg, out, stats);

    finalize_kernel<<<2048, 256, 0, stream>>>(stats, gamma, beta, node_feats, out);
}

// Round 9
// 316.399 us; speedup vs baseline: 2.0325x; 1.0734x over previous
//
#include <hip/hip_runtime.h>

#define N_NODES 100000
#define N_EDGES 1600000
#define F 128
#define BN_EPS 1e-5f
#define NB 391                        // node buckets of 256: ceil(100000/256)

// Workspace layout (bytes), all 64-aligned, NO overlaps:
//   [0, 1024)              stats: 256 floats (sum, sumsq)
//   [1024, 2592)           bcnt:  392 ints (bucket histogram)     } memset 0
//   [2592, 4160)           bbase: 392 ints (bucket exclusive scan)
//   [4160, 29184)          bcursor: 391 ints padded to 64B (idx*16)
//   [29184, 429184)        deg:     N_NODES ints
//   [429248, 829252)       offsets: N_NODES+1 ints
//   [829312, 7229312)      csr_src: N_EDGES ints
//   [7229376, 7262144)     Wb:      128*128 bf16
//   [7262144, 32862144)    aggb:    N_NODES*128 bf16 (gather output)
//                          binned (N_EDGES ints, 6.4MB) ALIASES aggb region
//   [32862144, 58462144)   Xb:      N_NODES*128 bf16 (bf16 copy of X)
#define O_STATS   0
#define O_BCNT    1024
#define O_BBASE   2592
#define O_BCUR    4160
#define O_DEG     29184
#define O_OFF     429248
#define O_CSR     829312
#define O_WB      7229376
#define O_AGGB    7262144
#define O_XB      32862144

typedef __attribute__((ext_vector_type(8))) short bf16x8;
typedef __attribute__((ext_vector_type(4))) float f32x4;

__device__ __forceinline__ unsigned short f2bf(float f) {
    union { float f; unsigned u; } v; v.f = f;
    unsigned u = v.u;
    unsigned r = u + 0x7FFFu + ((u >> 16) & 1u);   // round-to-nearest-even
    return (unsigned short)(r >> 16);
}

__device__ __forceinline__ float4 bf4_to_f4(ushort4 u) {
    union { unsigned u; float f; } a, b, c, d;
    a.u = (unsigned)u.x << 16; b.u = (unsigned)u.y << 16;
    c.u = (unsigned)u.z << 16; d.u = (unsigned)u.w << 16;
    return make_float4(a.f, b.f, c.f, d.f);
}

// ---------------------------------------------------------------------------
// K0a: convert W to bf16
// ---------------------------------------------------------------------------
__global__ __launch_bounds__(256) void convert_w(
    const float* __restrict__ W, unsigned short* __restrict__ Wb)
{
    int i = blockIdx.x * blockDim.x + threadIdx.x;
    Wb[i] = f2bf(W[i]);
}

// ---------------------------------------------------------------------------
// K0b: convert X to bf16 (one float4 -> ushort4 per thread)
// ---------------------------------------------------------------------------
__global__ __launch_bounds__(256) void convert_x(
    const float* __restrict__ X, unsigned short* __restrict__ Xb)
{
    int i = blockIdx.x * blockDim.x + threadIdx.x;   // 3.2M float4 total
    float4 v = ((const float4*)X)[i];
    ushort4 o;
    o.x = f2bf(v.x); o.y = f2bf(v.y); o.z = f2bf(v.z); o.w = f2bf(v.w);
    ((ushort4*)Xb)[i] = o;
}

// ---------------------------------------------------------------------------
// K1: bucket histogram of dst>>8, LDS-preaggregated (8 edges/thread)
// ---------------------------------------------------------------------------
__global__ __launch_bounds__(256) void bucket_hist(
    const int* __restrict__ dst, int* __restrict__ bcnt)
{
    __shared__ int h[NB];
    const int t = threadIdx.x;
    for (int i = t; i < NB; i += 256) h[i] = 0;
    __syncthreads();

    int e = (blockIdx.x * blockDim.x + t) * 8;
    if (e + 7 < N_EDGES) {
        int4 a = *(const int4*)&dst[e];
        int4 b = *(const int4*)&dst[e + 4];
        atomicAdd(&h[a.x >> 8], 1); atomicAdd(&h[a.y >> 8], 1);
        atomicAdd(&h[a.z >> 8], 1); atomicAdd(&h[a.w >> 8], 1);
        atomicAdd(&h[b.x >> 8], 1); atomicAdd(&h[b.y >> 8], 1);
        atomicAdd(&h[b.z >> 8], 1); atomicAdd(&h[b.w >> 8], 1);
    } else {
        for (; e < N_EDGES; ++e) atomicAdd(&h[dst[e] >> 8], 1);
    }
    __syncthreads();
    for (int i = t; i < NB; i += 256) {
        int v = h[i];
        if (v) atomicAdd(&bcnt[i], v);
    }
}

// ---------------------------------------------------------------------------
// K2: single block: exclusive scan of 391 bucket counts -> bbase, bcursor
// ---------------------------------------------------------------------------
__global__ __launch_bounds__(512) void bucket_scan(
    const int* __restrict__ bcnt,
    int* __restrict__ bbase,
    int* __restrict__ bcursor)
{
    const int t = threadIdx.x;
    __shared__ int ls[512];
    int v = (t < NB) ? bcnt[t] : 0;
    ls[t] = v;
    __syncthreads();
    for (int d = 1; d < 512; d <<= 1) {
        int u = (t >= d) ? ls[t - d] : 0;
        __syncthreads();
        ls[t] += u;
        __syncthreads();
    }
    if (t < NB) {
        int ex = ls[t] - v;
        bbase[t] = ex;
        bcursor[t * 16] = ex;        // 64B-padded cursor
    }
    if (t == NB - 1) bbase[NB] = ls[t];   // = N_EDGES
}

// ---------------------------------------------------------------------------
// K3: bin edges: binned[cursor[dst>>8]++] = (dst&255)<<17 | src
// ---------------------------------------------------------------------------
__global__ __launch_bounds__(256) void bin_fill(
    const int* __restrict__ src,
    const int* __restrict__ dst,
    int* __restrict__ bcursor,
    int* __restrict__ binned)
{
    int e = (blockIdx.x * blockDim.x + threadIdx.x) * 4;
    if (e + 3 < N_EDGES) {
        int4 s4 = *(const int4*)&src[e];
        int4 d4 = *(const int4*)&dst[e];
        int p0 = atomicAdd(&bcursor[(d4.x >> 8) * 16], 1);
        int p1 = atomicAdd(&bcursor[(d4.y >> 8) * 16], 1);
        int p2 = atomicAdd(&bcursor[(d4.z >> 8) * 16], 1);
        int p3 = atomicAdd(&bcursor[(d4.w >> 8) * 16], 1);
        binned[p0] = ((d4.x & 255) << 17) | s4.x;
        binned[p1] = ((d4.y & 255) << 17) | s4.y;
        binned[p2] = ((d4.z & 255) << 17) | s4.z;
        binned[p3] = ((d4.w & 255) << 17) | s4.w;
    } else {
        for (; e < N_EDGES; ++e) {
            int d = dst[e];
            int p = atomicAdd(&bcursor[(d >> 8) * 16], 1);
            binned[p] = ((d & 255) << 17) | src[e];
        }
    }
}

// ---------------------------------------------------------------------------
// K4: per-bucket CSR build. One block per bucket (256 nodes).
// ---------------------------------------------------------------------------
__global__ __launch_bounds__(256) void csr_build(
    const int* __restrict__ binned,
    const int* __restrict__ bbase,
    int* __restrict__ offsets,
    int* __restrict__ deg,
    int* __restrict__ csr_src)
{
    const int b   = blockIdx.x;
    const int t   = threadIdx.x;
    const int beg = bbase[b];
    const int end = bbase[b + 1];
    const int nb0 = b * 256;

    __shared__ int cnt[256];
    __shared__ int ls[256];
    __shared__ int cur[256];
    cnt[t] = 0;
    __syncthreads();

    for (int i = beg + t; i < end; i += 256)
        atomicAdd(&cnt[binned[i] >> 17], 1);
    __syncthreads();

    int v = cnt[t];
    ls[t] = v;
    __syncthreads();
    for (int d = 1; d < 256; d <<= 1) {
        int u = (t >= d) ? ls[t - d] : 0;
        __syncthreads();
        ls[t] += u;
        __syncthreads();
    }
    int ex = beg + ls[t] - v;        // global exclusive offset for node nb0+t
    cur[t] = ex;
    int node = nb0 + t;
    if (node < N_NODES) {
        offsets[node] = ex;
        deg[node]     = v;
    }
    if (b == NB - 1 && t == 0) offsets[N_NODES] = N_EDGES;
    __syncthreads();

    for (int i = beg + t; i < end; i += 256) {
        int w   = binned[i];
        int pos = atomicAdd(&cur[w >> 17], 1);
        csr_src[pos] = w & 0x1FFFF;
    }
}

// ---------------------------------------------------------------------------
// K5: pull-gather from bf16 X: aggb[v] = bf16( Xb[v] + sum Xb[src] ), fp32 acc.
// 32 lanes/node, ushort4 (8B) per lane = 256B/row. Unroll 8/4/1.
// ---------------------------------------------------------------------------
__global__ __launch_bounds__(256) void gather_kernel(
    const unsigned short* __restrict__ Xb,
    const int* __restrict__ offsets,
    const int* __restrict__ csr_src,
    unsigned short* __restrict__ aggb)
{
    int g    = blockIdx.x * 8 + (threadIdx.x >> 5);   // node id
    int lane = threadIdx.x & 31;
    if (g >= N_NODES) return;

    const ushort4* X4 = (const ushort4*)Xb;           // row = 32 ushort4
    float4 acc = bf4_to_f4(X4[(size_t)g * 32 + lane]);   // self loop

    int beg = offsets[g];
    int end = offsets[g + 1];

    int e = beg;
    for (; e + 7 < end; e += 8) {
        ushort4 u0 = X4[(size_t)csr_src[e]     * 32 + lane];
        ushort4 u1 = X4[(size_t)csr_src[e + 1] * 32 + lane];
        ushort4 u2 = X4[(size_t)csr_src[e + 2] * 32 + lane];
        ushort4 u3 = X4[(size_t)csr_src[e + 3] * 32 + lane];
        ushort4 u4 = X4[(size_t)csr_src[e + 4] * 32 + lane];
        ushort4 u5 = X4[(size_t)csr_src[e + 5] * 32 + lane];
        ushort4 u6 = X4[(size_t)csr_src[e + 6] * 32 + lane];
        ushort4 u7 = X4[(size_t)csr_src[e + 7] * 32 + lane];
        float4 v0 = bf4_to_f4(u0), v1 = bf4_to_f4(u1);
        float4 v2 = bf4_to_f4(u2), v3 = bf4_to_f4(u3);
        float4 v4 = bf4_to_f4(u4), v5 = bf4_to_f4(u5);
        float4 v6 = bf4_to_f4(u6), v7 = bf4_to_f4(u7);
        acc.x += v0.x + v1.x + v2.x + v3.x + v4.x + v5.x + v6.x + v7.x;
        acc.y += v0.y + v1.y + v2.y + v3.y + v4.y + v5.y + v6.y + v7.y;
        acc.z += v0.z + v1.z + v2.z + v3.z + v4.z + v5.z + v6.z + v7.z;
        acc.w += v0.w + v1.w + v2.w + v3.w + v4.w + v5.w + v6.w + v7.w;
    }
    if (e + 3 < end) {
        ushort4 u0 = X4[(size_t)csr_src[e]     * 32 + lane];
        ushort4 u1 = X4[(size_t)csr_src[e + 1] * 32 + lane];
        ushort4 u2 = X4[(size_t)csr_src[e + 2] * 32 + lane];
        ushort4 u3 = X4[(size_t)csr_src[e + 3] * 32 + lane];
        float4 v0 = bf4_to_f4(u0), v1 = bf4_to_f4(u1);
        float4 v2 = bf4_to_f4(u2), v3 = bf4_to_f4(u3);
        acc.x += v0.x + v1.x + v2.x + v3.x;
        acc.y += v0.y + v1.y + v2.y + v3.y;
        acc.z += v0.z + v1.z + v2.z + v3.z;
        acc.w += v0.w + v1.w + v2.w + v3.w;
        e += 4;
    }
    for (; e < end; ++e) {
        float4 v0 = bf4_to_f4(X4[(size_t)csr_src[e] * 32 + lane]);
        acc.x += v0.x; acc.y += v0.y; acc.z += v0.z; acc.w += v0.w;
    }
    ushort4 o;
    o.x = f2bf(acc.x); o.y = f2bf(acc.y); o.z = f2bf(acc.z); o.w = f2bf(acc.w);
    ((ushort4*)aggb)[(size_t)g * 32 + lane] = o;
}

// ---------------------------------------------------------------------------
// K6: MFMA GEMM: out = aggb @ Wb^T + (deg+1)*b, BN-stats in epilogue.
// ---------------------------------------------------------------------------
__global__ __launch_bounds__(256) void gemm_mfma(
    const unsigned short* __restrict__ Ab,   // [N,128] bf16
    const unsigned short* __restrict__ Wb,   // [128,128] bf16 [out][in]
    const float* __restrict__ bias,          // [128] fp32
    const int* __restrict__ deg,
    float* __restrict__ out,
    float* __restrict__ stats)
{
    const int t   = threadIdx.x;
    const int w   = t >> 6;          // wave 0..3
    const int l   = t & 63;
    const int l16 = l & 15;
    const int lk  = l >> 4;          // 0..3 (k-group / row-group)
    const int rowbase = blockIdx.x * 64 + w * 16;

    int arow = rowbase + l16;
    int arow_c = (arow < N_NODES) ? arow : 0;

    f32x4 acc[8];
#pragma unroll
    for (int nt = 0; nt < 8; nt++) acc[nt] = (f32x4){0.f, 0.f, 0.f, 0.f};

    const bf16x8* A8 = (const bf16x8*)Ab;
    const bf16x8* W8 = (const bf16x8*)Wb;

#pragma unroll
    for (int ks = 0; ks < 4; ks++) {
        bf16x8 a = A8[(size_t)arow_c * 16 + ks * 4 + lk];
#pragma unroll
        for (int nt = 0; nt < 8; nt++) {
            int col = nt * 16 + l16;
            bf16x8 b = W8[(size_t)col * 16 + ks * 4 + lk];
            acc[nt] = __builtin_amdgcn_mfma_f32_16x16x32_bf16(a, b, acc[nt], 0, 0, 0);
        }
    }

    float bv[8];
#pragma unroll
    for (int nt = 0; nt < 8; nt++) bv[nt] = bias[nt * 16 + l16];

    float sums[8], ssqs[8];
#pragma unroll
    for (int nt = 0; nt < 8; nt++) { sums[nt] = 0.f; ssqs[nt] = 0.f; }

    const int orow = rowbase + lk * 4;
#pragma unroll
    for (int r = 0; r < 4; r++) {
        int row = orow + r;
        if (row < N_NODES) {
            float scale = (float)(deg[row] + 1);
#pragma unroll
            for (int nt = 0; nt < 8; nt++) {
                float o = acc[nt][r] + scale * bv[nt];
                out[(size_t)row * F + nt * 16 + l16] = o;
                sums[nt] += o;
                ssqs[nt] += o * o;
            }
        }
    }

#pragma unroll
    for (int nt = 0; nt < 8; nt++) {
        sums[nt] += __shfl_xor(sums[nt], 16);
        sums[nt] += __shfl_xor(sums[nt], 32);
        ssqs[nt] += __shfl_xor(ssqs[nt], 16);
        ssqs[nt] += __shfl_xor(ssqs[nt], 32);
    }

    __shared__ float red0[128];
    __shared__ float red1[128];
    if (t < 128) { red0[t] = 0.f; red1[t] = 0.f; }
    __syncthreads();
    if (lk == 0) {
#pragma unroll
        for (int nt = 0; nt < 8; nt++) {
            int col = nt * 16 + l16;
            atomicAdd(&red0[col], sums[nt]);
            atomicAdd(&red1[col], ssqs[nt]);
        }
    }
    __syncthreads();
    if (t < 128) {
        unsafeAtomicAdd(&stats[t],       red0[t]);
        unsafeAtomicAdd(&stats[128 + t], red1[t]);
    }
}

// ---------------------------------------------------------------------------
// K7: out = relu(gamma*(agg-mean)*rsqrt(var+eps)+beta) + node_feats (in place)
// ---------------------------------------------------------------------------
__global__ __launch_bounds__(256) void finalize_kernel(
    const float* __restrict__ stats,
    const float* __restrict__ gamma,
    const float* __restrict__ beta,
    const float* __restrict__ x,
    float* __restrict__ agg)
{
    __shared__ float s_scale[128];
    __shared__ float s_shift[128];
    const int t = threadIdx.x;
    if (t < 128) {
        const float inv_n = 1.0f / (float)N_NODES;
        float mean = stats[t] * inv_n;
        float var  = stats[128 + t] * inv_n - mean * mean;
        float sc   = gamma[t] * rsqrtf(var + BN_EPS);
        s_scale[t] = sc;
        s_shift[t] = beta[t] - mean * sc;
    }
    __syncthreads();

    const long long total = (long long)N_NODES * F / 4;
    long long i0 = (long long)blockIdx.x * blockDim.x + t;
    for (long long i = i0; i < total; i += (long long)gridDim.x * blockDim.x) {
        int cb = (int)(i & 31) * 4;
        float4 v  = ((const float4*)agg)[i];
        float4 xf = ((const float4*)x)[i];
        float4 o;
        o.x = fmaxf(v.x * s_scale[cb + 0] + s_shift[cb + 0], 0.f) + xf.x;
        o.y = fmaxf(v.y * s_scale[cb + 1] + s_shift[cb + 1], 0.f) + xf.y;
        o.z = fmaxf(v.z * s_scale[cb + 2] + s_shift[cb + 2], 0.f) + xf.z;
        o.w = fmaxf(v.w * s_scale[cb + 3] + s_shift[cb + 3], 0.f) + xf.w;
        ((float4*)agg)[i] = o;
    }
}

// ---------------------------------------------------------------------------
extern "C" void kernel_launch(void* const* d_in, const int* in_sizes, int n_in,
                              void* d_out, int out_size, void* d_ws, size_t ws_size,
                              hipStream_t stream) {
    const float* node_feats = (const float*)d_in[0];
    const float* W          = (const float*)d_in[1];
    const float* b          = (const float*)d_in[2];
    const float* gamma      = (const float*)d_in[3];
    const float* beta       = (const float*)d_in[4];
    const int*   src        = (const int*)d_in[5];
    const int*   dst        = (const int*)d_in[6];

    float* out     = (float*)d_out;
    char*  ws      = (char*)d_ws;
    float* stats   = (float*)(ws + O_STATS);
    int*   bcnt    = (int*)(ws + O_BCNT);
    int*   bbase   = (int*)(ws + O_BBASE);
    int*   bcursor = (int*)(ws + O_BCUR);
    int*   deg     = (int*)(ws + O_DEG);
    int*   offsets = (int*)(ws + O_OFF);
    int*   csr_src = (int*)(ws + O_CSR);
    unsigned short* Wb   = (unsigned short*)(ws + O_WB);
    unsigned short* aggb = (unsigned short*)(ws + O_AGGB);
    unsigned short* Xb   = (unsigned short*)(ws + O_XB);
    int*   binned  = (int*)(ws + O_AGGB);   // aliases aggb (dead before gather)

    // zero stats + bcnt
    hipMemsetAsync(d_ws, 0, O_BBASE, stream);

    convert_w<<<64, 256, 0, stream>>>(W, Wb);
    convert_x<<<(N_NODES * F / 4) / 256, 256, 0, stream>>>(node_feats, Xb);

    bucket_hist<<<(N_EDGES / 8 + 255) / 256, 256, 0, stream>>>(dst, bcnt);
    bucket_scan<<<1, 512, 0, stream>>>(bcnt, bbase, bcursor);
    bin_fill<<<(N_EDGES / 4 + 255) / 256, 256, 0, stream>>>(src, dst, bcursor, binned);
    csr_build<<<NB, 256, 0, stream>>>(binned, bbase, offsets, deg, csr_src);

    gather_kernel<<<(N_NODES + 7) / 8, 256, 0, stream>>>(Xb, offsets, csr_src, aggb);

    gemm_mfma<<<(N_NODES + 63) / 64, 256, 0, stream>>>(aggb, Wb, b, deg, out, stats);

    finalize_kernel<<<2048, 256, 0, stream>>>(stats, gamma, beta, node_feats, out);
}

// Round 10
// 231.930 us; speedup vs baseline: 2.7727x; 1.3642x over previous
//
#include <hip/hip_runtime.h>

#define N_NODES 100000
#define N_EDGES 1600000
#define F 128
#define BN_EPS 1e-5f
#define NB 391                        // node buckets of 256: ceil(100000/256)
#define NBP 392                       // padded
#define CAP 5120                      // per-bucket capacity in binned (avg 4092, max ~4400)
#define EPB 4096                      // edges per bin_fill block
#define FILL_BLOCKS ((N_EDGES + EPB - 1) / EPB)   // 391

// Workspace layout (bytes), all 64-aligned, NO overlaps:
//   [0, 1024)              stats: 256 floats (sum, sumsq)          } memset 0
//   [1024, 2588)           gcur:  NB ints (bucket write cursors, init i*CAP)
//   [2624, 4192)           bbase: NB+1 ints (dense csr base per bucket)
//   [29184, 429184)        deg:     N_NODES ints
//   [429248, 829252)       offsets: N_NODES+1 ints
//   [829312, 7229312)      csr_src: N_EDGES ints
//   [7229376, 7262144)     Wb:      128*128 bf16
//   [7262144, 32862144)    aggb:    N_NODES*128 bf16 (gather output)
//                          binned (NB*CAP ints = 8.0MB) ALIASES aggb region
//   [32862144, 58462144)   Xb:      N_NODES*128 bf16 (bf16 copy of X)
#define O_STATS   0
#define O_GCUR    1024
#define O_BBASE   2624
#define O_DEG     29184
#define O_OFF     429248
#define O_CSR     829312
#define O_WB      7229376
#define O_AGGB    7262144
#define O_XB      32862144

typedef __attribute__((ext_vector_type(8))) short bf16x8;
typedef __attribute__((ext_vector_type(4))) float f32x4;

__device__ __forceinline__ unsigned short f2bf(float f) {
    union { float f; unsigned u; } v; v.f = f;
    unsigned u = v.u;
    unsigned r = u + 0x7FFFu + ((u >> 16) & 1u);   // round-to-nearest-even
    return (unsigned short)(r >> 16);
}

__device__ __forceinline__ float4 bf4_to_f4(ushort4 u) {
    union { unsigned u; float f; } a, b, c, d;
    a.u = (unsigned)u.x << 16; b.u = (unsigned)u.y << 16;
    c.u = (unsigned)u.z << 16; d.u = (unsigned)u.w << 16;
    return make_float4(a.f, b.f, c.f, d.f);
}

// ---------------------------------------------------------------------------
// K0a: convert W to bf16
// ---------------------------------------------------------------------------
__global__ __launch_bounds__(256) void convert_w(
    const float* __restrict__ W, unsigned short* __restrict__ Wb)
{
    int i = blockIdx.x * blockDim.x + threadIdx.x;
    Wb[i] = f2bf(W[i]);
}

// ---------------------------------------------------------------------------
// K0b: convert X to bf16
// ---------------------------------------------------------------------------
__global__ __launch_bounds__(256) void convert_x(
    const float* __restrict__ X, unsigned short* __restrict__ Xb)
{
    int i = blockIdx.x * blockDim.x + threadIdx.x;
    float4 v = ((const float4*)X)[i];
    ushort4 o;
    o.x = f2bf(v.x); o.y = f2bf(v.y); o.z = f2bf(v.z); o.w = f2bf(v.w);
    ((ushort4*)Xb)[i] = o;
}

// ---------------------------------------------------------------------------
// K0c: init bucket cursors: gcur[i] = i*CAP
// ---------------------------------------------------------------------------
__global__ __launch_bounds__(256) void init_cur(int* __restrict__ gcur)
{
    int i = blockIdx.x * blockDim.x + threadIdx.x;
    if (i < NB) gcur[i] = i * CAP;
}

// ---------------------------------------------------------------------------
// K1: multi-split bin fill. Each block: 4096 edges -> LDS count per bucket ->
// pair-scan -> ONE global atomic per (block,bucket) reserving a contiguous
// run -> LDS staging sorted by bucket -> coalesced run write-out.
// Writes to binned are block-private contiguous runs => full 64B lines from
// one XCD (fixes R9's 81MB WRITE_SIZE: cross-XCD 4B scatter never merged).
// ---------------------------------------------------------------------------
__global__ __launch_bounds__(256) void bin_fill(
    const int* __restrict__ src,
    const int* __restrict__ dst,
    int* __restrict__ gcur,
    int* __restrict__ binned)
{
    __shared__ int hcnt[NBP];           // counts -> placement cursors
    __shared__ int hloc[NBP];           // local exclusive base in staging
    __shared__ int hbase[NB];           // reserved global base
    __shared__ int ls[256];             // scan temp
    __shared__ int stage[EPB];          // staged packed edges (sorted by bucket)
    __shared__ unsigned short sbkt[EPB];

    const int t  = threadIdx.x;
    const int eb = blockIdx.x * EPB;

    for (int i = t; i < NBP; i += 256) hcnt[i] = 0;
    __syncthreads();

    // ---- load + count (static reg indexing; valid bitmask) ---------------
    int v[16]; int bkt[16];
    unsigned valid = 0;
#pragma unroll
    for (int k = 0; k < 4; k++) {
        int base = eb + t * 4 + k * 1024;
        if (base + 3 < N_EDGES) {
            int4 s4 = *(const int4*)&src[base];
            int4 d4 = *(const int4*)&dst[base];
            bkt[k*4+0] = d4.x >> 8; v[k*4+0] = ((d4.x & 255) << 17) | s4.x;
            bkt[k*4+1] = d4.y >> 8; v[k*4+1] = ((d4.y & 255) << 17) | s4.y;
            bkt[k*4+2] = d4.z >> 8; v[k*4+2] = ((d4.z & 255) << 17) | s4.z;
            bkt[k*4+3] = d4.w >> 8; v[k*4+3] = ((d4.w & 255) << 17) | s4.w;
            valid |= 0xFu << (k * 4);
            atomicAdd(&hcnt[bkt[k*4+0]], 1);
            atomicAdd(&hcnt[bkt[k*4+1]], 1);
            atomicAdd(&hcnt[bkt[k*4+2]], 1);
            atomicAdd(&hcnt[bkt[k*4+3]], 1);
        } else {
#pragma unroll
            for (int j = 0; j < 4; j++) {
                int e = base + j;
                if (e < N_EDGES) {
                    int d = dst[e];
                    bkt[k*4+j] = d >> 8;
                    v[k*4+j]   = ((d & 255) << 17) | src[e];
                    valid |= 1u << (k * 4 + j);
                    atomicAdd(&hcnt[bkt[k*4+j]], 1);
                } else { bkt[k*4+j] = 0; v[k*4+j] = 0; }
            }
        }
    }
    __syncthreads();

    // ---- pair-scan of 392 counts with 256 threads -------------------------
    int a0 = (2 * t     < NBP) ? hcnt[2 * t]     : 0;
    int a1 = (2 * t + 1 < NBP) ? hcnt[2 * t + 1] : 0;
    ls[t] = a0 + a1;
    __syncthreads();
    for (int d = 1; d < 256; d <<= 1) {
        int u = (t >= d) ? ls[t - d] : 0;
        __syncthreads();
        ls[t] += u;
        __syncthreads();
    }
    int pb = ls[t] - (a0 + a1);        // exclusive base of this pair
    if (2 * t     < NBP) hloc[2 * t]     = pb;
    if (2 * t + 1 < NBP) hloc[2 * t + 1] = pb + a0;
    __syncthreads();

    // ---- reserve global runs (1 atomic per non-empty bucket) --------------
    for (int i = t; i < NB; i += 256) {
        int c = hcnt[i];
        hbase[i] = c ? atomicAdd(&gcur[i], c) : 0;
    }
    __syncthreads();

    // ---- convert hcnt into placement cursors ------------------------------
    for (int i = t; i < NBP; i += 256) hcnt[i] = hloc[i];
    __syncthreads();

    // ---- place into staging, sorted by bucket ------------------------------
#pragma unroll
    for (int k = 0; k < 16; k++) {
        if (valid & (1u << k)) {
            int p = atomicAdd(&hcnt[bkt[k]], 1);
            stage[p] = v[k];
            sbkt[p]  = (unsigned short)bkt[k];
        }
    }
    __syncthreads();

    // ---- coalesced write-out of per-bucket runs ----------------------------
    int m = min(EPB, N_EDGES - eb);
#pragma unroll
    for (int k = 0; k < 16; k++) {
        int p = t + k * 256;
        if (p < m) {
            int b = sbkt[p];
            binned[hbase[b] + (p - hloc[b])] = stage[p];
        }
    }
}

// ---------------------------------------------------------------------------
// K2: single block: bucket counts from final cursors -> dense csr bases
// ---------------------------------------------------------------------------
__global__ __launch_bounds__(512) void bucket_scan(
    const int* __restrict__ gcur,
    int* __restrict__ bbase)
{
    const int t = threadIdx.x;
    __shared__ int ls[512];
    int c = (t < NB) ? (gcur[t] - t * CAP) : 0;
    ls[t] = c;
    __syncthreads();
    for (int d = 1; d < 512; d <<= 1) {
        int u = (t >= d) ? ls[t - d] : 0;
        __syncthreads();
        ls[t] += u;
        __syncthreads();
    }
    if (t < NB) bbase[t] = ls[t] - c;
    if (t == NB - 1) bbase[NB] = ls[t];   // = N_EDGES
}

// ---------------------------------------------------------------------------
// K3: per-bucket CSR build. One block per bucket (256 nodes).
// Reads the bucket's gapped region [b*CAP, gcur[b]); writes dense csr.
// ---------------------------------------------------------------------------
__global__ __launch_bounds__(256) void csr_build(
    const int* __restrict__ binned,
    const int* __restrict__ gcur,
    const int* __restrict__ bbase,
    int* __restrict__ offsets,
    int* __restrict__ deg,
    int* __restrict__ csr_src)
{
    const int b    = blockIdx.x;
    const int t    = threadIdx.x;
    const int rbeg = b * CAP;
    const int rend = gcur[b];            // rbeg + count
    const int wofs = bbase[b] - rbeg;    // map staged pos -> dense pos
    const int nb0  = b * 256;

    __shared__ int cnt[256];
    __shared__ int ls[256];
    __shared__ int cur[256];
    cnt[t] = 0;
    __syncthreads();

    for (int i = rbeg + t; i < rend; i += 256)
        atomicAdd(&cnt[binned[i] >> 17], 1);
    __syncthreads();

    int v = cnt[t];
    ls[t] = v;
    __syncthreads();
    for (int d = 1; d < 256; d <<= 1) {
        int u = (t >= d) ? ls[t - d] : 0;
        __syncthreads();
        ls[t] += u;
        __syncthreads();
    }
    int ex = bbase[b] + ls[t] - v;       // dense exclusive offset for node nb0+t
    cur[t] = ex;
    int node = nb0 + t;
    if (node < N_NODES) {
        offsets[node] = ex;
        deg[node]     = v;
    }
    if (b == NB - 1 && t == 0) offsets[N_NODES] = N_EDGES;
    __syncthreads();

    for (int i = rbeg + t; i < rend; i += 256) {
        int w   = binned[i];
        int pos = atomicAdd(&cur[w >> 17], 1);
        csr_src[pos] = w & 0x1FFFF;
    }
}

// ---------------------------------------------------------------------------
// K4: pull-gather from bf16 X: aggb[v] = bf16( Xb[v] + sum Xb[src] ), fp32 acc.
// ---------------------------------------------------------------------------
__global__ __launch_bounds__(256) void gather_kernel(
    const unsigned short* __restrict__ Xb,
    const int* __restrict__ offsets,
    const int* __restrict__ csr_src,
    unsigned short* __restrict__ aggb)
{
    int g    = blockIdx.x * 8 + (threadIdx.x >> 5);   // node id
    int lane = threadIdx.x & 31;
    if (g >= N_NODES) return;

    const ushort4* X4 = (const ushort4*)Xb;           // row = 32 ushort4
    float4 acc = bf4_to_f4(X4[(size_t)g * 32 + lane]);   // self loop

    int beg = offsets[g];
    int end = offsets[g + 1];

    int e = beg;
    for (; e + 7 < end; e += 8) {
        ushort4 u0 = X4[(size_t)csr_src[e]     * 32 + lane];
        ushort4 u1 = X4[(size_t)csr_src[e + 1] * 32 + lane];
        ushort4 u2 = X4[(size_t)csr_src[e + 2] * 32 + lane];
        ushort4 u3 = X4[(size_t)csr_src[e + 3] * 32 + lane];
        ushort4 u4 = X4[(size_t)csr_src[e + 4] * 32 + lane];
        ushort4 u5 = X4[(size_t)csr_src[e + 5] * 32 + lane];
        ushort4 u6 = X4[(size_t)csr_src[e + 6] * 32 + lane];
        ushort4 u7 = X4[(size_t)csr_src[e + 7] * 32 + lane];
        float4 v0 = bf4_to_f4(u0), v1 = bf4_to_f4(u1);
        float4 v2 = bf4_to_f4(u2), v3 = bf4_to_f4(u3);
        float4 v4 = bf4_to_f4(u4), v5 = bf4_to_f4(u5);
        float4 v6 = bf4_to_f4(u6), v7 = bf4_to_f4(u7);
        acc.x += v0.x + v1.x + v2.x + v3.x + v4.x + v5.x + v6.x + v7.x;
        acc.y += v0.y + v1.y + v2.y + v3.y + v4.y + v5.y + v6.y + v7.y;
        acc.z += v0.z + v1.z + v2.z + v3.z + v4.z + v5.z + v6.z + v7.z;
        acc.w += v0.w + v1.w + v2.w + v3.w + v4.w + v5.w + v6.w + v7.w;
    }
    if (e + 3 < end) {
        ushort4 u0 = X4[(size_t)csr_src[e]     * 32 + lane];
        ushort4 u1 = X4[(size_t)csr_src[e + 1] * 32 + lane];
        ushort4 u2 = X4[(size_t)csr_src[e + 2] * 32 + lane];
        ushort4 u3 = X4[(size_t)csr_src[e + 3] * 32 + lane];
        float4 v0 = bf4_to_f4(u0), v1 = bf4_to_f4(u1);
        float4 v2 = bf4_to_f4(u2), v3 = bf4_to_f4(u3);
        acc.x += v0.x + v1.x + v2.x + v3.x;
        acc.y += v0.y + v1.y + v2.y + v3.y;
        acc.z += v0.z + v1.z + v2.z + v3.z;
        acc.w += v0.w + v1.w + v2.w + v3.w;
        e += 4;
    }
    for (; e < end; ++e) {
        float4 v0 = bf4_to_f4(X4[(size_t)csr_src[e] * 32 + lane]);
        acc.x += v0.x; acc.y += v0.y; acc.z += v0.z; acc.w += v0.w;
    }
    ushort4 o;
    o.x = f2bf(acc.x); o.y = f2bf(acc.y); o.z = f2bf(acc.z); o.w = f2bf(acc.w);
    ((ushort4*)aggb)[(size_t)g * 32 + lane] = o;
}

// ---------------------------------------------------------------------------
// K5: MFMA GEMM: out = aggb @ Wb^T + (deg+1)*b, BN-stats in epilogue.
// ---------------------------------------------------------------------------
__global__ __launch_bounds__(256) void gemm_mfma(
    const unsigned short* __restrict__ Ab,   // [N,128] bf16
    const unsigned short* __restrict__ Wb,   // [128,128] bf16 [out][in]
    const float* __restrict__ bias,          // [128] fp32
    const int* __restrict__ deg,
    float* __restrict__ out,
    float* __restrict__ stats)
{
    const int t   = threadIdx.x;
    const int w   = t >> 6;          // wave 0..3
    const int l   = t & 63;
    const int l16 = l & 15;
    const int lk  = l >> 4;          // 0..3 (k-group / row-group)
    const int rowbase = blockIdx.x * 64 + w * 16;

    int arow = rowbase + l16;
    int arow_c = (arow < N_NODES) ? arow : 0;

    f32x4 acc[8];
#pragma unroll
    for (int nt = 0; nt < 8; nt++) acc[nt] = (f32x4){0.f, 0.f, 0.f, 0.f};

    const bf16x8* A8 = (const bf16x8*)Ab;
    const bf16x8* W8 = (const bf16x8*)Wb;

#pragma unroll
    for (int ks = 0; ks < 4; ks++) {
        bf16x8 a = A8[(size_t)arow_c * 16 + ks * 4 + lk];
#pragma unroll
        for (int nt = 0; nt < 8; nt++) {
            int col = nt * 16 + l16;
            bf16x8 b = W8[(size_t)col * 16 + ks * 4 + lk];
            acc[nt] = __builtin_amdgcn_mfma_f32_16x16x32_bf16(a, b, acc[nt], 0, 0, 0);
        }
    }

    float bv[8];
#pragma unroll
    for (int nt = 0; nt < 8; nt++) bv[nt] = bias[nt * 16 + l16];

    float sums[8], ssqs[8];
#pragma unroll
    for (int nt = 0; nt < 8; nt++) { sums[nt] = 0.f; ssqs[nt] = 0.f; }

    const int orow = rowbase + lk * 4;
#pragma unroll
    for (int r = 0; r < 4; r++) {
        int row = orow + r;
        if (row < N_NODES) {
            float scale = (float)(deg[row] + 1);
#pragma unroll
            for (int nt = 0; nt < 8; nt++) {
                float o = acc[nt][r] + scale * bv[nt];
                out[(size_t)row * F + nt * 16 + l16] = o;
                sums[nt] += o;
                ssqs[nt] += o * o;
            }
        }
    }

#pragma unroll
    for (int nt = 0; nt < 8; nt++) {
        sums[nt] += __shfl_xor(sums[nt], 16);
        sums[nt] += __shfl_xor(sums[nt], 32);
        ssqs[nt] += __shfl_xor(ssqs[nt], 16);
        ssqs[nt] += __shfl_xor(ssqs[nt], 32);
    }

    __shared__ float red0[128];
    __shared__ float red1[128];
    if (t < 128) { red0[t] = 0.f; red1[t] = 0.f; }
    __syncthreads();
    if (lk == 0) {
#pragma unroll
        for (int nt = 0; nt < 8; nt++) {
            int col = nt * 16 + l16;
            atomicAdd(&red0[col], sums[nt]);
            atomicAdd(&red1[col], ssqs[nt]);
        }
    }
    __syncthreads();
    if (t < 128) {
        unsafeAtomicAdd(&stats[t],       red0[t]);
        unsafeAtomicAdd(&stats[128 + t], red1[t]);
    }
}

// ---------------------------------------------------------------------------
// K6: out = relu(gamma*(agg-mean)*rsqrt(var+eps)+beta) + node_feats (in place)
// ---------------------------------------------------------------------------
__global__ __launch_bounds__(256) void finalize_kernel(
    const float* __restrict__ stats,
    const float* __restrict__ gamma,
    const float* __restrict__ beta,
    const float* __restrict__ x,
    float* __restrict__ agg)
{
    __shared__ float s_scale[128];
    __shared__ float s_shift[128];
    const int t = threadIdx.x;
    if (t < 128) {
        const float inv_n = 1.0f / (float)N_NODES;
        float mean = stats[t] * inv_n;
        float var  = stats[128 + t] * inv_n - mean * mean;
        float sc   = gamma[t] * rsqrtf(var + BN_EPS);
        s_scale[t] = sc;
        s_shift[t] = beta[t] - mean * sc;
    }
    __syncthreads();

    const long long total = (long long)N_NODES * F / 4;
    long long i0 = (long long)blockIdx.x * blockDim.x + t;
    for (long long i = i0; i < total; i += (long long)gridDim.x * blockDim.x) {
        int cb = (int)(i & 31) * 4;
        float4 v  = ((const float4*)agg)[i];
        float4 xf = ((const float4*)x)[i];
        float4 o;
        o.x = fmaxf(v.x * s_scale[cb + 0] + s_shift[cb + 0], 0.f) + xf.x;
        o.y = fmaxf(v.y * s_scale[cb + 1] + s_shift[cb + 1], 0.f) + xf.y;
        o.z = fmaxf(v.z * s_scale[cb + 2] + s_shift[cb + 2], 0.f) + xf.z;
        o.w = fmaxf(v.w * s_scale[cb + 3] + s_shift[cb + 3], 0.f) + xf.w;
        ((float4*)agg)[i] = o;
    }
}

// ---------------------------------------------------------------------------
extern "C" void kernel_launch(void* const* d_in, const int* in_sizes, int n_in,
                              void* d_out, int out_size, void* d_ws, size_t ws_size,
                              hipStream_t stream) {
    const float* node_feats = (const float*)d_in[0];
    const float* W          = (const float*)d_in[1];
    const float* b          = (const float*)d_in[2];
    const float* gamma      = (const float*)d_in[3];
    const float* beta       = (const float*)d_in[4];
    const int*   src        = (const int*)d_in[5];
    const int*   dst        = (const int*)d_in[6];

    float* out     = (float*)d_out;
    char*  ws      = (char*)d_ws;
    float* stats   = (float*)(ws + O_STATS);
    int*   gcur    = (int*)(ws + O_GCUR);
    int*   bbase   = (int*)(ws + O_BBASE);
    int*   deg     = (int*)(ws + O_DEG);
    int*   offsets = (int*)(ws + O_OFF);
    int*   csr_src = (int*)(ws + O_CSR);
    unsigned short* Wb   = (unsigned short*)(ws + O_WB);
    unsigned short* aggb = (unsigned short*)(ws + O_AGGB);
    unsigned short* Xb   = (unsigned short*)(ws + O_XB);
    int*   binned  = (int*)(ws + O_AGGB);   // aliases aggb (dead before gather)

    // zero stats
    hipMemsetAsync(d_ws, 0, 1024, stream);

    convert_w<<<64, 256, 0, stream>>>(W, Wb);
    convert_x<<<(N_NODES * F / 4) / 256, 256, 0, stream>>>(node_feats, Xb);
    init_cur<<<2, 256, 0, stream>>>(gcur);

    bin_fill<<<FILL_BLOCKS, 256, 0, stream>>>(src, dst, gcur, binned);
    bucket_scan<<<1, 512, 0, stream>>>(gcur, bbase);
    csr_build<<<NB, 256, 0, stream>>>(binned, gcur, bbase, offsets, deg, csr_src);

    gather_kernel<<<(N_NODES + 7) / 8, 256, 0, stream>>>(Xb, offsets, csr_src, aggb);

    gemm_mfma<<<(N_NODES + 63) / 64, 256, 0, stream>>>(aggb, Wb, b, deg, out, stats);

    finalize_kernel<<<2048, 256, 0, stream>>>(stats, gamma, beta, node_feats, out);
}